// Round 10
// baseline (1201.578 us; speedup 1.0000x reference)
//
#include <hip/hip_runtime.h>
#include <hip/hip_bf16.h>

#define HID 128
#define SEQ 512
#define INS 14
#define BC 16
#define NPAIR 128
#define RING_R 4
// K0 = 160 : [x(14) | 1 | pad->32 | h0(128)]   -> 5 k-steps of 32
// K1 = 256 : [h0(128) | h1(128)]               -> 8 k-steps of 32
#define X0STRIDE 40
#define X1LSTRIDE 136   // A-local h0 double buffer stride (128 + 8 pad)
#define X1STRIDE 264    // B [h0|h1] double buffer stride (256 + 8 pad)
#define NFRAG0 10240          // 8 unit-groups * 4 gates * 5 ksteps * 64 lanes
#define NFRAG1 16384          // 8 unit-groups * 4 gates * 8 ksteps * 64 lanes
#define W1BASE (NFRAG0 * 8)   // short offset of W1 region in ws
#define RINGOFF ((NFRAG0 + NFRAG1) * 16)            // byte offset of h0 ring
#define FLAGOFF (RINGOFF + NPAIR * RING_R * 4096)   // byte offset of flags

typedef __attribute__((ext_vector_type(8))) short bs8;
typedef __attribute__((ext_vector_type(4))) float f4;
typedef unsigned long long u64t;

__device__ __forceinline__ short f2bf(float f) {
    union { float f; unsigned u; } a; a.f = f;
    unsigned u = a.u;
    u += 0x7fffu + ((u >> 16) & 1u);   // RNE
    return (short)(u >> 16);
}
__device__ __forceinline__ float bf2f(short s) {
    union { unsigned u; float f; } a;
    a.u = ((unsigned)(unsigned short)s) << 16;
    return a.f;
}
__device__ __forceinline__ float sigm(float x) {
    return __builtin_amdgcn_rcpf(1.f + __builtin_amdgcn_exp2f(x * -1.44269504f));
}
__device__ __forceinline__ int aflag(int* p) {
    return __hip_atomic_load(p, __ATOMIC_RELAXED, __HIP_MEMORY_SCOPE_AGENT);
}

// ---------------------------------------------------------------------------
// prep: swizzle weights into MFMA B-fragment order (bf16 bits) + reset the
// producer/consumer flags to -1 (runs every launch, before the main kernel
// on the same stream -> graph-replay safe).
// ---------------------------------------------------------------------------
__global__ void lstm_prep(
    const float* __restrict__ Wih0, const float* __restrict__ Whh0,
    const float* __restrict__ bih0, const float* __restrict__ bhh0,
    const float* __restrict__ Wih1, const float* __restrict__ Whh1,
    short* __restrict__ wsw)
{
    if (blockIdx.x == 0 && threadIdx.x < 2 * NPAIR)
        ((int*)((char*)wsw + FLAGOFF))[threadIdx.x] = -1;
    int f = blockIdx.x * 256 + threadIdx.x;
    if (f >= NFRAG0 + NFRAG1) return;
    if (f < NFRAG0) {
        int lane = f & 63, t = f >> 6;
        int ks = t % 5, gw = t / 5, g = gw & 3, wv = gw >> 2;
        int row = g * HID + wv * 16 + (lane & 15);
        int kbase = ks * 32 + (lane >> 4) * 8;
        for (int j = 0; j < 8; ++j) {
            int k = kbase + j;
            float v;
            if (k < INS)        v = Wih0[row * INS + k];
            else if (k == INS)  v = bih0[row] + bhh0[row];
            else if (k < 32)    v = 0.f;
            else                v = Whh0[row * HID + (k - 32)];
            wsw[f * 8 + j] = f2bf(v);
        }
    } else {
        int fl = f - NFRAG0;
        int lane = fl & 63, t = fl >> 6;
        int ks = t & 7, g = (t >> 3) & 3, wv = t >> 5;
        int row = g * HID + wv * 16 + (lane & 15);
        int kbase = ks * 32 + (lane >> 4) * 8;
        for (int j = 0; j < 8; ++j) {
            int k = kbase + j;
            float v = (k < HID) ? Wih1[row * HID + k] : Whh1[row * HID + (k - HID)];
            wsw[f * 8 + j] = f2bf(v);
        }
    }
}

// ---------------------------------------------------------------------------
// main. Round-10: LAYER-PIPELINE SPLIT ACROSS BLOCK PAIRS (use all 256 CUs).
// r5/r6/r8/r9 closed every intra-CU lever at 2 waves/SIMD; the remaining
// structural waste was grid=128 on 256 CUs. Role by blockIdx&1:
//   A (role 0): L0 only — x stage, 20 MFMA, CELL0; h0(t) kept locally (xh1l)
//     for its own ks1-4 AND published to a 4-slot global ring as device-scope
//     relaxed 8B atomic stores ([unit][row] layout -> 1 store/lane) which
//     bypass the non-coherent XCD L2s and land in IC. prodFlag=t after a
//     barrier (vmcnt drained).
//   B (role 1): L1 only — ALL 32 W1 frags in registers (wlds eliminated),
//     h0(t) arrives via ring (8B atomic load/thread, prefetched one step
//     ahead mid-MFMA so IC latency hides), h1 state local, CELL1, final FC.
// Flow control: A waits consFlag >= t-R before reusing a slot; B waits
// prodFlag >= t. Deadlock-free given co-residency, which is FORCED by
// LDS > 80 KB (1 block/CU) x grid 256 = #CUs. Numerics identical to r7.
// ---------------------------------------------------------------------------
__global__ __attribute__((amdgpu_flat_work_group_size(512, 512)))
__attribute__((amdgpu_waves_per_eu(2, 2))) void lstm_fused(
    const float* __restrict__ x,
    const float* __restrict__ Wfc,  const float* __restrict__ bfc,
    const float* __restrict__ bih1, const float* __restrict__ bhh1,
    short* __restrict__ wsw,
    float* __restrict__ out)
{
    __shared__ __align__(16) short xh0[2][BC][X0STRIDE];    // A: x tile
    __shared__ __align__(16) short xh1l[2][BC][X1LSTRIDE];  // A: local h0
    __shared__ __align__(16) short xh1[2][BC][X1STRIDE];    // B: [h0|h1]
    __shared__ short lds_pad[28672];  // 56 KB pad -> block LDS ~84 KB -> 1 block/CU

    const int tid  = threadIdx.x;
    const int lane = tid & 63;
    const int wv   = tid >> 6;      // 0..7
    const int col  = lane & 15;
    const int quad = lane >> 4;
    const int u    = wv * 16 + col; // hidden unit owned by this lane
    const int role = blockIdx.x & 1;
    const int pair = blockIdx.x >> 1;
    const int b0   = pair * BC;
    const int aoff = quad * 8;

    if (bfc[0] > 1.0e30f) lds_pad[tid] = 1;   // keep pad alive (never true)

    char* ws    = (char*)wsw;
    char* ring  = ws + RINGOFF + (size_t)pair * RING_R * 4096;
    int*  prodF = (int*)(ws + FLAGOFF) + pair;
    int*  consF = (int*)(ws + FLAGOFF) + NPAIR + pair;

    // merged-denominator LSTM cell (r4/r7 numerics): 5 exp2 + 2 rcp per row
#define CELLH(A0, A1, A2, A3, cvar, r, HOUT) { \
        float ei = __builtin_amdgcn_exp2f(A0[r] * -1.44269504f); \
        float ef = __builtin_amdgcn_exp2f(A1[r] * -1.44269504f); \
        float eg = __builtin_amdgcn_exp2f(A2[r] * -2.88539008f); \
        float eo = __builtin_amdgcn_exp2f(A3[r] * -1.44269504f); \
        float Di = 1.f + ei, Df = 1.f + ef, Dg = 1.f + eg, Do = 1.f + eo; \
        float rP = __builtin_amdgcn_rcpf(Df * Di * Dg); \
        float num = __builtin_fmaf(cvar * Di, Dg, (1.f - eg) * Df); \
        cvar = num * rP; \
        float ec = __builtin_amdgcn_exp2f(cvar * -2.88539008f); \
        float rQ = __builtin_amdgcn_rcpf((1.f + ec) * Do); \
        HOUT = (1.f - ec) * rQ; }

    if (role == 0) {
        // =================== A: layer 0 producer ===================
        const short* wb0 = wsw + ((wv * 20) * 64 + lane) * 8;
#define DW0(g,ks) const bs8 w0_##g##_##ks = *(const bs8*)(wb0 + ((g)*5+(ks))*512);
        DW0(0,0) DW0(0,1) DW0(0,2) DW0(0,3) DW0(0,4)
        DW0(1,0) DW0(1,1) DW0(1,2) DW0(1,3) DW0(1,4)
        DW0(2,0) DW0(2,1) DW0(2,2) DW0(2,3) DW0(2,4)
        DW0(3,0) DW0(3,1) DW0(3,2) DW0(3,3) DW0(3,4)
#define L0K(ks, AF) { \
        acc0_0 = __builtin_amdgcn_mfma_f32_16x16x32_bf16(AF, w0_0_##ks, acc0_0, 0,0,0); \
        acc0_1 = __builtin_amdgcn_mfma_f32_16x16x32_bf16(AF, w0_1_##ks, acc0_1, 0,0,0); \
        acc0_2 = __builtin_amdgcn_mfma_f32_16x16x32_bf16(AF, w0_2_##ks, acc0_2, 0,0,0); \
        acc0_3 = __builtin_amdgcn_mfma_f32_16x16x32_bf16(AF, w0_3_##ks, acc0_3, 0,0,0); }

        for (int idx = tid; idx < 2 * BC * X0STRIDE; idx += 512) ((short*)xh0)[idx] = 0;
        for (int idx = tid; idx < 2 * BC * X1LSTRIDE; idx += 512) ((short*)xh1l)[idx] = 0;
        __syncthreads();
        if (tid < 2 * BC) xh0[tid >> 4][tid & 15][INS] = (short)0x3f80;  // 1.0 bf16

        const int  xm = wv * 2 + (lane >> 5);   // batch row 0..15
        const int  xi = lane & 31;
        const bool xldr = (xi < INS);
        const float* xp = xldr ? (x + ((size_t)(b0 + xm) * SEQ) * INS + xi) : x;
        float xv = xldr ? xp[0] : 0.f;
        float c0_0 = 0.f, c0_1 = 0.f, c0_2 = 0.f, c0_3 = 0.f;

        for (int t = 0; t < SEQ; ++t) {
            const int p = t & 1, q = p ^ 1;
            if (xldr) xh0[p][xm][xi] = f2bf(xv);
            float xnext = (xldr && (t + 1 < SEQ)) ? xp[(t + 1) * INS] : 0.f;
            __syncthreads();  // x(t) + h0(t-1) visible

            const bs8 afx = *(const bs8*)&xh0[p][col][aoff];
            const bs8 af0 = *(const bs8*)&xh1l[p][col][0 * 32 + aoff];
            const bs8 af1 = *(const bs8*)&xh1l[p][col][1 * 32 + aoff];
            const bs8 af2 = *(const bs8*)&xh1l[p][col][2 * 32 + aoff];
            const bs8 af3 = *(const bs8*)&xh1l[p][col][3 * 32 + aoff];
            f4 acc0_0 = {0.f,0.f,0.f,0.f}, acc0_1 = {0.f,0.f,0.f,0.f};
            f4 acc0_2 = {0.f,0.f,0.f,0.f}, acc0_3 = {0.f,0.f,0.f,0.f};
            L0K(0, afx) L0K(1, af0) L0K(2, af1) L0K(3, af2) L0K(4, af3)

            float h0_, h1_, h2_, h3_;
            CELLH(acc0_0, acc0_1, acc0_2, acc0_3, c0_0, 0, h0_)
            CELLH(acc0_0, acc0_1, acc0_2, acc0_3, c0_1, 1, h1_)
            CELLH(acc0_0, acc0_1, acc0_2, acc0_3, c0_2, 2, h2_)
            CELLH(acc0_0, acc0_1, acc0_2, acc0_3, c0_3, 3, h3_)
            unsigned pk0, pk1;
            asm("v_cvt_pk_bf16_f32 %0, %1, %2" : "=v"(pk0) : "v"(h0_), "v"(h1_));
            asm("v_cvt_pk_bf16_f32 %0, %1, %2" : "=v"(pk1) : "v"(h2_), "v"(h3_));
            // local copy for own ks1-4 next step
            xh1l[q][quad * 4 + 0][u] = (short)pk0;
            xh1l[q][quad * 4 + 1][u] = (short)(pk0 >> 16);
            xh1l[q][quad * 4 + 2][u] = (short)pk1;
            xh1l[q][quad * 4 + 3][u] = (short)(pk1 >> 16);
            // ring publish: wait for slot to be free, then 1x 8B atomic store
            if (t >= RING_R) { while (aflag(consF) < t - RING_R) {} }
            u64t pkv = (u64t)pk0 | ((u64t)pk1 << 32);
            __hip_atomic_store(
                (u64t*)(ring + (t & (RING_R - 1)) * 4096 + u * 32 + quad * 8),
                pkv, __ATOMIC_RELAXED, __HIP_MEMORY_SCOPE_AGENT);
            __syncthreads();  // drains vmcnt for ALL waves before the flag
            if (tid == 0)
                __hip_atomic_store(prodF, t, __ATOMIC_RELAXED, __HIP_MEMORY_SCOPE_AGENT);
            xv = xnext;
        }
    } else {
        // =================== B: layer 1 consumer ===================
        const short* wb1 = wsw + W1BASE + ((wv * 32) * 64 + lane) * 8;
#define DW1(g,ks) const bs8 w1_##g##_##ks = *(const bs8*)(wb1 + ((g)*8+(ks))*512);
        DW1(0,0) DW1(0,1) DW1(0,2) DW1(0,3) DW1(0,4) DW1(0,5) DW1(0,6) DW1(0,7)
        DW1(1,0) DW1(1,1) DW1(1,2) DW1(1,3) DW1(1,4) DW1(1,5) DW1(1,6) DW1(1,7)
        DW1(2,0) DW1(2,1) DW1(2,2) DW1(2,3) DW1(2,4) DW1(2,5) DW1(2,6) DW1(2,7)
        DW1(3,0) DW1(3,1) DW1(3,2) DW1(3,3) DW1(3,4) DW1(3,5) DW1(3,6) DW1(3,7)
#define L1K(ks, AF) { \
        acc1_0 = __builtin_amdgcn_mfma_f32_16x16x32_bf16(AF, w1_0_##ks, acc1_0, 0,0,0); \
        acc1_1 = __builtin_amdgcn_mfma_f32_16x16x32_bf16(AF, w1_1_##ks, acc1_1, 0,0,0); \
        acc1_2 = __builtin_amdgcn_mfma_f32_16x16x32_bf16(AF, w1_2_##ks, acc1_2, 0,0,0); \
        acc1_3 = __builtin_amdgcn_mfma_f32_16x16x32_bf16(AF, w1_3_##ks, acc1_3, 0,0,0); }

        const float b1_0 = bih1[0 * HID + u] + bhh1[0 * HID + u];
        const float b1_1 = bih1[1 * HID + u] + bhh1[1 * HID + u];
        const float b1_2 = bih1[2 * HID + u] + bhh1[2 * HID + u];
        const float b1_3 = bih1[3 * HID + u] + bhh1[3 * HID + u];

        for (int idx = tid; idx < 2 * BC * X1STRIDE; idx += 512) ((short*)xh1)[idx] = 0;
        __syncthreads();

        const int runit = tid >> 2;        // unit 0..127
        const int rrow0 = (tid & 3) * 4;   // rows r0..r0+3
        while (aflag(prodF) < 0) {}
        u64t hpre = __hip_atomic_load((u64t*)(ring + tid * 8),
                                      __ATOMIC_RELAXED, __HIP_MEMORY_SCOPE_AGENT);
        float c1_0 = 0.f, c1_1 = 0.f, c1_2 = 0.f, c1_3 = 0.f;

        for (int t = 0; t < SEQ; ++t) {
            const int p = t & 1, q = p ^ 1;
            // h0(t) regs -> LDS
            xh1[p][rrow0 + 0][runit] = (short)hpre;
            xh1[p][rrow0 + 1][runit] = (short)(hpre >> 16);
            xh1[p][rrow0 + 2][runit] = (short)(hpre >> 32);
            xh1[p][rrow0 + 3][runit] = (short)(hpre >> 48);
            __syncthreads();  // h0(t) + h1(t-1) visible; also: all waves consumed hpre
            if (tid == 0)
                __hip_atomic_store(consF, t, __ATOMIC_RELAXED, __HIP_MEMORY_SCOPE_AGENT);

            const bs8 af0 = *(const bs8*)&xh1[p][col][0 * 32 + aoff];
            const bs8 af1 = *(const bs8*)&xh1[p][col][1 * 32 + aoff];
            const bs8 af2 = *(const bs8*)&xh1[p][col][2 * 32 + aoff];
            const bs8 af3 = *(const bs8*)&xh1[p][col][3 * 32 + aoff];
            const bs8 af4 = *(const bs8*)&xh1[p][col][4 * 32 + aoff];
            const bs8 af5 = *(const bs8*)&xh1[p][col][5 * 32 + aoff];
            const bs8 af6 = *(const bs8*)&xh1[p][col][6 * 32 + aoff];
            const bs8 af7 = *(const bs8*)&xh1[p][col][7 * 32 + aoff];

            f4 acc1_0 = {b1_0, b1_0, b1_0, b1_0};
            f4 acc1_1 = {b1_1, b1_1, b1_1, b1_1};
            f4 acc1_2 = {b1_2, b1_2, b1_2, b1_2};
            f4 acc1_3 = {b1_3, b1_3, b1_3, b1_3};
            L1K(0, af0) L1K(1, af1) L1K(2, af2) L1K(3, af3)
            // prefetch h0(t+1) mid-MFMA: IC latency hides under ks4-7 + CELL1
            if (t + 1 < SEQ) {
                while (aflag(prodF) < t + 1) {}
                hpre = __hip_atomic_load(
                    (u64t*)(ring + ((t + 1) & (RING_R - 1)) * 4096 + tid * 8),
                    __ATOMIC_RELAXED, __HIP_MEMORY_SCOPE_AGENT);
            }
            L1K(4, af4) L1K(5, af5) L1K(6, af6) L1K(7, af7)

            float g0_, g1_, g2_, g3_;
            CELLH(acc1_0, acc1_1, acc1_2, acc1_3, c1_0, 0, g0_)
            CELLH(acc1_0, acc1_1, acc1_2, acc1_3, c1_1, 1, g1_)
            CELLH(acc1_0, acc1_1, acc1_2, acc1_3, c1_2, 2, g2_)
            CELLH(acc1_0, acc1_1, acc1_2, acc1_3, c1_3, 3, g3_)
            unsigned pk0, pk1;
            asm("v_cvt_pk_bf16_f32 %0, %1, %2" : "=v"(pk0) : "v"(g0_), "v"(g1_));
            asm("v_cvt_pk_bf16_f32 %0, %1, %2" : "=v"(pk1) : "v"(g2_), "v"(g3_));
            xh1[q][quad * 4 + 0][HID + u] = (short)pk0;
            xh1[q][quad * 4 + 1][HID + u] = (short)(pk0 >> 16);
            xh1[q][quad * 4 + 2][HID + u] = (short)pk1;
            xh1[q][quad * 4 + 3][HID + u] = (short)(pk1 >> 16);
            // no second barrier: next iter's ds_writes hit xh1[q][0..127],
            // disjoint from these [HID+...] stores; reads guarded by next barrier
        }
        __syncthreads();

        // final FC (128 -> 1) + sigmoid; h1(SEQ-1) in xh1[0] (t=511 -> q=0)
        if (tid < BC) {
            float s = bfc[0];
#pragma unroll 8
            for (int k2 = 0; k2 < HID; ++k2)
                s += bf2f(xh1[0][tid][HID + k2]) * Wfc[k2];
            out[b0 + tid] = sigm(s);
        }
    }
}

extern "C" void kernel_launch(void* const* d_in, const int* in_sizes, int n_in,
                              void* d_out, int out_size, void* d_ws, size_t ws_size,
                              hipStream_t stream) {
    const float* x    = (const float*)d_in[0];
    const float* Wih0 = (const float*)d_in[1];
    const float* Whh0 = (const float*)d_in[2];
    const float* bih0 = (const float*)d_in[3];
    const float* bhh0 = (const float*)d_in[4];
    const float* Wih1 = (const float*)d_in[5];
    const float* Whh1 = (const float*)d_in[6];
    const float* bih1 = (const float*)d_in[7];
    const float* bhh1 = (const float*)d_in[8];
    const float* Wfc  = (const float*)d_in[9];
    const float* bfc  = (const float*)d_in[10];
    float* out = (float*)d_out;
    short* wsw = (short*)d_ws;   // 426 KB weights + 2 MB h0 ring + flags

    int nfrag = NFRAG0 + NFRAG1;
    lstm_prep<<<(nfrag + 255) / 256, 256, 0, stream>>>(Wih0, Whh0, bih0, bhh0,
                                                       Wih1, Whh1, wsw);
    dim3 grid(2 * NPAIR);   // 256 blocks = 128 (A=L0) + 128 (B=L1), 1 per CU
    dim3 block(512);
    lstm_fused<<<grid, block, 0, stream>>>(x, Wfc, bfc, bih1, bhh1, wsw, out);
}

// Round 11
// 1103.616 us; speedup vs baseline: 1.0888x; 1.0888x over previous
//
#include <hip/hip_runtime.h>
#include <hip/hip_bf16.h>

#define HID 128
#define SEQ 512
#define INS 14
#define BC 16
// K0 = 160 : [x(14) | 1 | pad->32 | h0(128)]   -> 5 k-steps of 32
// K1 = 256 : [h0(128) | h1(128)]               -> 8 k-steps of 32
#define X0STRIDE 40
#define X1STRIDE 264  // 256 + 8 pad shorts; row stride 132 dw = 4 mod 32 -> 2-way reads (free)
#define NFRAG0 10240          // 8 waves * 4 gates * 5 ksteps * 64 lanes
#define NFRAG1 16384          // 8 waves * 4 gates * 8 ksteps * 64 lanes
#define W1BASE (NFRAG0 * 8)   // short offset of W1 region in ws

typedef __attribute__((ext_vector_type(8))) short bs8;
typedef __attribute__((ext_vector_type(4))) float f4;

__device__ __forceinline__ short f2bf(float f) {
    union { float f; unsigned u; } a; a.f = f;
    unsigned u = a.u;
    u += 0x7fffu + ((u >> 16) & 1u);   // RNE
    return (short)(u >> 16);
}
__device__ __forceinline__ float bf2f(short s) {
    union { unsigned u; float f; } a;
    a.u = ((unsigned)(unsigned short)s) << 16;
    return a.f;
}
__device__ __forceinline__ float sigm(float x) {
    return __builtin_amdgcn_rcpf(1.f + __builtin_amdgcn_exp2f(x * -1.44269504f));
}

// ---------------------------------------------------------------------------
// prep: swizzle weights into MFMA B-fragment order in ws (bf16 bits).
// ---------------------------------------------------------------------------
__global__ void lstm_prep(
    const float* __restrict__ Wih0, const float* __restrict__ Whh0,
    const float* __restrict__ bih0, const float* __restrict__ bhh0,
    const float* __restrict__ Wih1, const float* __restrict__ Whh1,
    short* __restrict__ wsw)
{
    int f = blockIdx.x * 256 + threadIdx.x;
    if (f >= NFRAG0 + NFRAG1) return;
    if (f < NFRAG0) {
        int lane = f & 63, t = f >> 6;
        int ks = t % 5, gw = t / 5, g = gw & 3, wv = gw >> 2;
        int row = g * HID + wv * 16 + (lane & 15);
        int kbase = ks * 32 + (lane >> 4) * 8;
        for (int j = 0; j < 8; ++j) {
            int k = kbase + j;
            float v;
            if (k < INS)        v = Wih0[row * INS + k];
            else if (k == INS)  v = bih0[row] + bhh0[row];
            else if (k < 32)    v = 0.f;
            else                v = Whh0[row * HID + (k - 32)];
            wsw[f * 8 + j] = f2bf(v);
        }
    } else {
        int fl = f - NFRAG0;
        int lane = fl & 63, t = fl >> 6;
        int ks = t & 7, g = (t >> 3) & 3, wv = t >> 5;
        int row = g * HID + wv * 16 + (lane & 15);
        int kbase = ks * 32 + (lane >> 4) * 8;
        for (int j = 0; j < 8; ++j) {
            int k = kbase + j;
            float v = (k < HID) ? Wih1[row * HID + k] : Whh1[row * HID + (k - HID)];
            wsw[f * 8 + j] = f2bf(v);
        }
    }
}

// ---------------------------------------------------------------------------
// main. Round-11 = round-7 (best verified, 950 us) + SINGLE-VARIABLE test:
// L1 ks4-5 weight frags moved wlds -> registers (44 frags resident = 176
// regs; r7 had 36 = 144 @ 120 arch VGPR). wlds shrinks to ks6-7 (64 KB).
// Rationale: r7's LDS pipe carries (9 af + 16 wlds) b128/wave/step x 8
// waves = 200 reads ~ 1600+ cy of the 4450-cy step; wlds re-reads are 64%
// of that and exist only for register-capacity reasons. r8's version of
// this test was confounded by the swizzle's address math; this is clean.
// Outcomes: (a) -3..6% => LDS pipe co-critical, move ks6-7 next;
// (b) null => LDS not critical, plateau is barrier/latency-structural;
// (c) WRITE_SIZE MBs => spill wall at 44 frags, revert.
// r5/r6/r8/r9/r10 all falsified their hypotheses (journal in git).
// ---------------------------------------------------------------------------
__global__ __attribute__((amdgpu_flat_work_group_size(512, 512)))
__attribute__((amdgpu_waves_per_eu(2, 2))) void lstm_fused(
    const float* __restrict__ x,
    const float* __restrict__ Wfc,  const float* __restrict__ bfc,
    const float* __restrict__ bih1, const float* __restrict__ bhh1,
    const short* __restrict__ wsw,
    float* __restrict__ out)
{
    __shared__ __align__(16) short xh0[2][BC][X0STRIDE];
    __shared__ __align__(16) short xh1[2][BC][X1STRIDE];
    // L1 ks6-7 weights: [wv][ks-6][gate][lane][8] -> 64 KB, per-wave private
    __shared__ __align__(16) short wlds[8][2][4][64][8];

    const int tid  = threadIdx.x;
    const int lane = tid & 63;
    const int wv   = tid >> 6;      // 0..7
    const int col  = lane & 15;
    const int quad = lane >> 4;
    const int u    = wv * 16 + col; // hidden unit owned by this lane
    const int b0   = blockIdx.x * BC;

    // ---- register-resident weight fragments: L0 all 20, L1 ks0-5 (24) ----
    const short* wb0 = wsw + ((wv * 20) * 64 + lane) * 8;           // wv*4*5
    const short* wb1 = wsw + W1BASE + ((wv * 32) * 64 + lane) * 8;  // wv*4*8
#define DW0(g,ks) const bs8 w0_##g##_##ks = *(const bs8*)(wb0 + ((g)*5+(ks))*512);
#define DW1(g,ks) const bs8 w1_##g##_##ks = *(const bs8*)(wb1 + ((g)*8+(ks))*512);
    DW0(0,0) DW0(0,1) DW0(0,2) DW0(0,3) DW0(0,4)
    DW0(1,0) DW0(1,1) DW0(1,2) DW0(1,3) DW0(1,4)
    DW0(2,0) DW0(2,1) DW0(2,2) DW0(2,3) DW0(2,4)
    DW0(3,0) DW0(3,1) DW0(3,2) DW0(3,3) DW0(3,4)
    DW1(0,0) DW1(0,1) DW1(0,2) DW1(0,3) DW1(0,4) DW1(0,5)
    DW1(1,0) DW1(1,1) DW1(1,2) DW1(1,3) DW1(1,4) DW1(1,5)
    DW1(2,0) DW1(2,1) DW1(2,2) DW1(2,3) DW1(2,4) DW1(2,5)
    DW1(3,0) DW1(3,1) DW1(3,2) DW1(3,3) DW1(3,4) DW1(3,5)

    const float b1_0 = bih1[0 * HID + u] + bhh1[0 * HID + u];
    const float b1_1 = bih1[1 * HID + u] + bhh1[1 * HID + u];
    const float b1_2 = bih1[2 * HID + u] + bhh1[2 * HID + u];
    const float b1_3 = bih1[3 * HID + u] + bhh1[3 * HID + u];

    // ---- LDS init: zeros + constant-1 bias column + L1 ks6-7 weight tiles ----
    for (int idx = tid; idx < 2 * BC * X0STRIDE; idx += 512) ((short*)xh0)[idx] = 0;
    for (int idx = tid; idx < 2 * BC * X1STRIDE; idx += 512) ((short*)xh1)[idx] = 0;
#pragma unroll
    for (int f = 0; f < 8; ++f) {
        int m = f >> 2, g = f & 3;    // m = ks-6
        *(bs8*)&wlds[wv][m][g][lane][0] =
            *(const bs8*)(wsw + W1BASE +
                (((wv * 4 + g) * 8 + (m + 6)) * 64 + lane) * 8);
    }
    __syncthreads();
    if (tid < 2 * BC) xh0[tid >> 4][tid & 15][INS] = (short)0x3f80;  // 1.0 bf16

    // ---- x(t) staging: 2 batch rows per wave, 28 active lanes per wave ----
    const int  xm = wv * 2 + (lane >> 5);   // batch row 0..15
    const int  xi = lane & 31;              // input feature
    const bool xldr = (xi < INS);
    const float* xp = xldr ? (x + ((size_t)(b0 + xm) * SEQ) * INS + xi) : x;
    float xv = xldr ? xp[0] : 0.f;

    float c0_0 = 0.f, c0_1 = 0.f, c0_2 = 0.f, c0_3 = 0.f;
    float c1_0 = 0.f, c1_1 = 0.f, c1_2 = 0.f, c1_3 = 0.f;
    const int aoff = quad * 8;

    // ---- MFMA macros; AF passed explicitly (af temps shared L1<->L0) ----
#define L1KR(ks, AF) { \
        acc1_0 = __builtin_amdgcn_mfma_f32_16x16x32_bf16(AF, w1_0_##ks, acc1_0, 0,0,0); \
        acc1_1 = __builtin_amdgcn_mfma_f32_16x16x32_bf16(AF, w1_1_##ks, acc1_1, 0,0,0); \
        acc1_2 = __builtin_amdgcn_mfma_f32_16x16x32_bf16(AF, w1_2_##ks, acc1_2, 0,0,0); \
        acc1_3 = __builtin_amdgcn_mfma_f32_16x16x32_bf16(AF, w1_3_##ks, acc1_3, 0,0,0); }
#define L1KL(ks, AF) { \
        const bs8 u0 = *(const bs8*)&wlds[wv][(ks)-6][0][lane][0]; \
        const bs8 u1 = *(const bs8*)&wlds[wv][(ks)-6][1][lane][0]; \
        const bs8 u2 = *(const bs8*)&wlds[wv][(ks)-6][2][lane][0]; \
        const bs8 u3 = *(const bs8*)&wlds[wv][(ks)-6][3][lane][0]; \
        acc1_0 = __builtin_amdgcn_mfma_f32_16x16x32_bf16(AF, u0, acc1_0, 0,0,0); \
        acc1_1 = __builtin_amdgcn_mfma_f32_16x16x32_bf16(AF, u1, acc1_1, 0,0,0); \
        acc1_2 = __builtin_amdgcn_mfma_f32_16x16x32_bf16(AF, u2, acc1_2, 0,0,0); \
        acc1_3 = __builtin_amdgcn_mfma_f32_16x16x32_bf16(AF, u3, acc1_3, 0,0,0); }
#define L0K(ks, AF) { \
        acc0_0 = __builtin_amdgcn_mfma_f32_16x16x32_bf16(AF, w0_0_##ks, acc0_0, 0,0,0); \
        acc0_1 = __builtin_amdgcn_mfma_f32_16x16x32_bf16(AF, w0_1_##ks, acc0_1, 0,0,0); \
        acc0_2 = __builtin_amdgcn_mfma_f32_16x16x32_bf16(AF, w0_2_##ks, acc0_2, 0,0,0); \
        acc0_3 = __builtin_amdgcn_mfma_f32_16x16x32_bf16(AF, w0_3_##ks, acc0_3, 0,0,0); }

    // ---- merged-denominator LSTM cell: 5 exp2 + 2 rcp per row -> h value ----
#define CELLH(A0, A1, A2, A3, cvar, r, HOUT) { \
        float ei = __builtin_amdgcn_exp2f(A0[r] * -1.44269504f); \
        float ef = __builtin_amdgcn_exp2f(A1[r] * -1.44269504f); \
        float eg = __builtin_amdgcn_exp2f(A2[r] * -2.88539008f); \
        float eo = __builtin_amdgcn_exp2f(A3[r] * -1.44269504f); \
        float Di = 1.f + ei, Df = 1.f + ef, Dg = 1.f + eg, Do = 1.f + eo; \
        float rP = __builtin_amdgcn_rcpf(Df * Di * Dg); \
        float num = __builtin_fmaf(cvar * Di, Dg, (1.f - eg) * Df); \
        cvar = num * rP; \
        float ec = __builtin_amdgcn_exp2f(cvar * -2.88539008f); \
        float rQ = __builtin_amdgcn_rcpf((1.f + ec) * Do); \
        HOUT = (1.f - ec) * rQ; }

    // pack 2 h values (rows 2J, 2J+1 of this quad) with hw RNE, 2 b16 stores
#define STOREPAIR(HA, HB, J, ROW, COLOFF) { \
        unsigned pk; \
        asm("v_cvt_pk_bf16_f32 %0, %1, %2" : "=v"(pk) : "v"(HA), "v"(HB)); \
        xh1[ROW][quad * 4 + 2*(J)][(COLOFF) + u]     = (short)pk; \
        xh1[ROW][quad * 4 + 2*(J) + 1][(COLOFF) + u] = (short)(pk >> 16); }

#define CELL4_0(ROW) { \
        float h0_, h1_, h2_, h3_; \
        CELLH(acc0_0, acc0_1, acc0_2, acc0_3, c0_0, 0, h0_) \
        CELLH(acc0_0, acc0_1, acc0_2, acc0_3, c0_1, 1, h1_) \
        CELLH(acc0_0, acc0_1, acc0_2, acc0_3, c0_2, 2, h2_) \
        CELLH(acc0_0, acc0_1, acc0_2, acc0_3, c0_3, 3, h3_) \
        STOREPAIR(h0_, h1_, 0, ROW, 0) STOREPAIR(h2_, h3_, 1, ROW, 0) }

#define CELL1H(r, HOUT) CELLH(acc1_0, acc1_1, acc1_2, acc1_3, c1_##r, r, HOUT)

    // ---- prologue t=0: layer 0 only (h0(-1)=0 from zero-init) ----
    {
        const int p = 0, q = 1;
        if (xldr) xh0[p][xm][xi] = f2bf(xv);
        float xnext = xldr ? xp[INS] : 0.f;
        __syncthreads();
        const bs8 afx = *(const bs8*)&xh0[p][col][aoff];
        const bs8 af0 = *(const bs8*)&xh1[p][col][0 * 32 + aoff];
        const bs8 af1 = *(const bs8*)&xh1[p][col][1 * 32 + aoff];
        const bs8 af2 = *(const bs8*)&xh1[p][col][2 * 32 + aoff];
        const bs8 af3 = *(const bs8*)&xh1[p][col][3 * 32 + aoff];
        f4 acc0_0 = {0.f,0.f,0.f,0.f}, acc0_1 = {0.f,0.f,0.f,0.f};
        f4 acc0_2 = {0.f,0.f,0.f,0.f}, acc0_3 = {0.f,0.f,0.f,0.f};
        L0K(0, afx) L0K(1, af0) L0K(2, af1) L0K(3, af2) L0K(4, af3)
        CELL4_0(q)
        xv = xnext;
    }

    // ---- steady state: iter t does L1/CELL1 for t-1 and L0/CELL0 for t ----
    for (int t = 1; t < SEQ; ++t) {
        const int p = t & 1, q = p ^ 1;
        if (xldr) xh0[p][xm][xi] = f2bf(xv);
        float xnext = (xldr && (t + 1 < SEQ)) ? xp[(t + 1) * INS] : 0.f;
        __syncthreads();  // x(t), h0(t-1), h1(t-2) all visible in parity p

        // A-row burst: 9 ds_read_b128, loaded once, shared by L1 and L0
        const bs8 afx = *(const bs8*)&xh0[p][col][aoff];
        const bs8 af0 = *(const bs8*)&xh1[p][col][0 * 32 + aoff];
        const bs8 af1 = *(const bs8*)&xh1[p][col][1 * 32 + aoff];
        const bs8 af2 = *(const bs8*)&xh1[p][col][2 * 32 + aoff];
        const bs8 af3 = *(const bs8*)&xh1[p][col][3 * 32 + aoff];
        const bs8 af4 = *(const bs8*)&xh1[p][col][4 * 32 + aoff];
        const bs8 af5 = *(const bs8*)&xh1[p][col][5 * 32 + aoff];
        const bs8 af6 = *(const bs8*)&xh1[p][col][6 * 32 + aoff];
        const bs8 af7 = *(const bs8*)&xh1[p][col][7 * 32 + aoff];

        f4 acc1_0 = {b1_0, b1_0, b1_0, b1_0};
        f4 acc1_1 = {b1_1, b1_1, b1_1, b1_1};
        f4 acc1_2 = {b1_2, b1_2, b1_2, b1_2};
        f4 acc1_3 = {b1_3, b1_3, b1_3, b1_3};
        L1KR(0, af0) L1KR(1, af1) L1KR(2, af2) L1KR(3, af3)
        L1KR(4, af4) L1KR(5, af5)
        L1KL(6, af6) L1KL(7, af7)

        f4 acc0_0 = {0.f,0.f,0.f,0.f}, acc0_1 = {0.f,0.f,0.f,0.f};
        f4 acc0_2 = {0.f,0.f,0.f,0.f}, acc0_3 = {0.f,0.f,0.f,0.f};
        // interleave: matrix pipe (L0) and trans pipe (CELL1) concurrently
        float g0_, g1_, g2_, g3_;
        L0K(0, afx) CELL1H(0, g0_)
        L0K(1, af0) CELL1H(1, g1_)
        L0K(2, af1) CELL1H(2, g2_)
        L0K(3, af2) CELL1H(3, g3_)
        L0K(4, af3)
        STOREPAIR(g0_, g1_, 0, q, HID) STOREPAIR(g2_, g3_, 1, q, HID)
        CELL4_0(q)

        xv = xnext;
    }

    // ---- epilogue: L1/CELL1 for t = SEQ-1 (SEQ even -> parity 0) ----
    {
        const int p = 0, q = 1;
        __syncthreads();
        const bs8 af0 = *(const bs8*)&xh1[p][col][0 * 32 + aoff];
        const bs8 af1 = *(const bs8*)&xh1[p][col][1 * 32 + aoff];
        const bs8 af2 = *(const bs8*)&xh1[p][col][2 * 32 + aoff];
        const bs8 af3 = *(const bs8*)&xh1[p][col][3 * 32 + aoff];
        const bs8 af4 = *(const bs8*)&xh1[p][col][4 * 32 + aoff];
        const bs8 af5 = *(const bs8*)&xh1[p][col][5 * 32 + aoff];
        const bs8 af6 = *(const bs8*)&xh1[p][col][6 * 32 + aoff];
        const bs8 af7 = *(const bs8*)&xh1[p][col][7 * 32 + aoff];
        f4 acc1_0 = {b1_0, b1_0, b1_0, b1_0};
        f4 acc1_1 = {b1_1, b1_1, b1_1, b1_1};
        f4 acc1_2 = {b1_2, b1_2, b1_2, b1_2};
        f4 acc1_3 = {b1_3, b1_3, b1_3, b1_3};
        L1KR(0, af0) L1KR(1, af1) L1KR(2, af2) L1KR(3, af3)
        L1KR(4, af4) L1KR(5, af5)
        L1KL(6, af6) L1KL(7, af7)
        float g0_, g1_, g2_, g3_;
        CELL1H(0, g0_) CELL1H(1, g1_) CELL1H(2, g2_) CELL1H(3, g3_)
        STOREPAIR(g0_, g1_, 0, q, HID) STOREPAIR(g2_, g3_, 1, q, HID)
    }
    __syncthreads();

    // ---- final FC (128 -> 1) + sigmoid; h1(SEQ-1) lives in xh1[1][.][HID+..] ----
    if (tid < BC) {
        float s = bfc[0];
#pragma unroll 8
        for (int k2 = 0; k2 < HID; ++k2)
            s += bf2f(xh1[1][tid][HID + k2]) * Wfc[k2];
        out[b0 + tid] = sigm(s);
    }
}

extern "C" void kernel_launch(void* const* d_in, const int* in_sizes, int n_in,
                              void* d_out, int out_size, void* d_ws, size_t ws_size,
                              hipStream_t stream) {
    const float* x    = (const float*)d_in[0];
    const float* Wih0 = (const float*)d_in[1];
    const float* Whh0 = (const float*)d_in[2];
    const float* bih0 = (const float*)d_in[3];
    const float* bhh0 = (const float*)d_in[4];
    const float* Wih1 = (const float*)d_in[5];
    const float* Whh1 = (const float*)d_in[6];
    const float* bih1 = (const float*)d_in[7];
    const float* bhh1 = (const float*)d_in[8];
    const float* Wfc  = (const float*)d_in[9];
    const float* bfc  = (const float*)d_in[10];
    float* out = (float*)d_out;
    short* wsw = (short*)d_ws;   // 426 KB of bf16 fragment-ordered weights

    int nfrag = NFRAG0 + NFRAG1;
    lstm_prep<<<(nfrag + 255) / 256, 256, 0, stream>>>(Wih0, Whh0, bih0, bhh0,
                                                       Wih1, Whh1, wsw);
    dim3 grid(2048 / BC);   // 128 blocks, 1 per CU
    dim3 block(512);        // 8 waves; each wave owns 16 hidden units
    lstm_fused<<<grid, block, 0, stream>>>(x, Wfc, bfc, bih1, bhh1, wsw, out);
}

// Round 12
// 914.199 us; speedup vs baseline: 1.3144x; 1.2072x over previous
//
#include <hip/hip_runtime.h>
#include <hip/hip_bf16.h>

#define HID 128
#define SEQ 512
#define INS 14
#define BC 16
// K0 = 160 : [x(14) | 1 | pad->32 | h0(128)]   -> 5 k-steps of 32
// K1 = 256 : [h0(128) | h1(128)]               -> 8 k-steps of 32
#define X0STRIDE 40
#define X1STRIDE 264  // 256 + 8 pad shorts
#define NFRAG0 10240          // 8 waves * 4 gates * 5 ksteps * 64 lanes
#define NFRAG1 16384          // 8 waves * 4 gates * 8 ksteps * 64 lanes
#define W1BASE (NFRAG0 * 8)   // short offset of W1 region in ws

typedef __attribute__((ext_vector_type(8))) short bs8;
typedef __attribute__((ext_vector_type(4))) float f4;

__device__ __forceinline__ short f2bf(float f) {
    union { float f; unsigned u; } a; a.f = f;
    unsigned u = a.u;
    u += 0x7fffu + ((u >> 16) & 1u);   // RNE
    return (short)(u >> 16);
}
__device__ __forceinline__ float bf2f(short s) {
    union { unsigned u; float f; } a;
    a.u = ((unsigned)(unsigned short)s) << 16;
    return a.f;
}
__device__ __forceinline__ float sigm(float x) {
    return __builtin_amdgcn_rcpf(1.f + __builtin_amdgcn_exp2f(x * -1.44269504f));
}

// ---------------------------------------------------------------------------
// prep: swizzle weights into MFMA B-fragment order in ws (bf16 bits), with
// the exp2 gate constant FOLDED IN: gates i,f,o rows scaled by -log2(e)
// (-1.4427), tanh gate g rows by -2*log2(e) (-2.8854). The MFMA output is
// then directly the exp2 argument -> removes one v_mul per exp in the cell.
// ---------------------------------------------------------------------------
__global__ void lstm_prep(
    const float* __restrict__ Wih0, const float* __restrict__ Whh0,
    const float* __restrict__ bih0, const float* __restrict__ bhh0,
    const float* __restrict__ Wih1, const float* __restrict__ Whh1,
    short* __restrict__ wsw)
{
    int f = blockIdx.x * 256 + threadIdx.x;
    if (f >= NFRAG0 + NFRAG1) return;
    if (f < NFRAG0) {
        int lane = f & 63, t = f >> 6;
        int ks = t % 5, gw = t / 5, g = gw & 3, wv = gw >> 2;
        float sc = (g == 2) ? -2.88539008f : -1.44269504f;
        int row = g * HID + wv * 16 + (lane & 15);
        int kbase = ks * 32 + (lane >> 4) * 8;
        for (int j = 0; j < 8; ++j) {
            int k = kbase + j;
            float v;
            if (k < INS)        v = Wih0[row * INS + k];
            else if (k == INS)  v = bih0[row] + bhh0[row];
            else if (k < 32)    v = 0.f;
            else                v = Whh0[row * HID + (k - 32)];
            wsw[f * 8 + j] = f2bf(v * sc);
        }
    } else {
        int fl = f - NFRAG0;
        int lane = fl & 63, t = fl >> 6;
        int ks = t & 7, g = (t >> 3) & 3, wv = t >> 5;
        float sc = (g == 2) ? -2.88539008f : -1.44269504f;
        int row = g * HID + wv * 16 + (lane & 15);
        int kbase = ks * 32 + (lane >> 4) * 8;
        for (int j = 0; j < 8; ++j) {
            int k = kbase + j;
            float v = (k < HID) ? Wih1[row * HID + k] : Whh1[row * HID + (k - HID)];
            wsw[f * 8 + j] = f2bf(v * sc);
        }
    }
}

// ---------------------------------------------------------------------------
// main. Round-12 = round-7 restored (best verified, 950 us) + gate-constant
// folding (see prep): CELLH's 4 gate-exp2 now take the MFMA accumulator
// DIRECTLY (no v_mul); only ec (from live c) keeps its mul. Saves 32 VALU
// ops/thread/step in the dominant pipe (VALUBusy 29%), shortens acc->exp
// dependency. b1 biases scaled at load to match.
// Closed branches (counter evidence, r5-r11): wave de-phase, role-split
// 4w/SIMD, LDS swizzle, chain-split, cross-CU ring pipeline, reg/LDS
// rebalance in either direction. 36 reg-frags + 16 LDS-frags is the
// capacity-optimal split at 2 waves/SIMD (weights 416 KB/CU pin occupancy).
// Canaries: absmax <= 0.00390625 (else revert to r7); WRITE_SIZE ~8 B.
// ---------------------------------------------------------------------------
__global__ __attribute__((amdgpu_flat_work_group_size(512, 512)))
__attribute__((amdgpu_waves_per_eu(2, 2))) void lstm_fused(
    const float* __restrict__ x,
    const float* __restrict__ Wfc,  const float* __restrict__ bfc,
    const float* __restrict__ bih1, const float* __restrict__ bhh1,
    const short* __restrict__ wsw,
    float* __restrict__ out)
{
    __shared__ __align__(16) short xh0[2][BC][X0STRIDE];
    __shared__ __align__(16) short xh1[2][BC][X1STRIDE];
    // L1 ks4-7 weights: [wv][ks-4][gate][lane][8] -> 128 KB, per-wave private
    __shared__ __align__(16) short wlds[8][4][4][64][8];

    const int tid  = threadIdx.x;
    const int lane = tid & 63;
    const int wv   = tid >> 6;      // 0..7
    const int col  = lane & 15;
    const int quad = lane >> 4;
    const int u    = wv * 16 + col; // hidden unit owned by this lane
    const int b0   = blockIdx.x * BC;

    // ---- register-resident weight fragments: L0 all 20, L1 ks0-3 (16) ----
    const short* wb0 = wsw + ((wv * 20) * 64 + lane) * 8;           // wv*4*5
    const short* wb1 = wsw + W1BASE + ((wv * 32) * 64 + lane) * 8;  // wv*4*8
#define DW0(g,ks) const bs8 w0_##g##_##ks = *(const bs8*)(wb0 + ((g)*5+(ks))*512);
#define DW1(g,ks) const bs8 w1_##g##_##ks = *(const bs8*)(wb1 + ((g)*8+(ks))*512);
    DW0(0,0) DW0(0,1) DW0(0,2) DW0(0,3) DW0(0,4)
    DW0(1,0) DW0(1,1) DW0(1,2) DW0(1,3) DW0(1,4)
    DW0(2,0) DW0(2,1) DW0(2,2) DW0(2,3) DW0(2,4)
    DW0(3,0) DW0(3,1) DW0(3,2) DW0(3,3) DW0(3,4)
    DW1(0,0) DW1(0,1) DW1(0,2) DW1(0,3)
    DW1(1,0) DW1(1,1) DW1(1,2) DW1(1,3)
    DW1(2,0) DW1(2,1) DW1(2,2) DW1(2,3)
    DW1(3,0) DW1(3,1) DW1(3,2) DW1(3,3)

    // biases pre-scaled by the same gate constants as the weights
    const float b1_0 = (bih1[0 * HID + u] + bhh1[0 * HID + u]) * -1.44269504f;
    const float b1_1 = (bih1[1 * HID + u] + bhh1[1 * HID + u]) * -1.44269504f;
    const float b1_2 = (bih1[2 * HID + u] + bhh1[2 * HID + u]) * -2.88539008f;
    const float b1_3 = (bih1[3 * HID + u] + bhh1[3 * HID + u]) * -1.44269504f;

    // ---- LDS init: zeros + constant-1 bias column + L1 ks4-7 weight tiles ----
    for (int idx = tid; idx < 2 * BC * X0STRIDE; idx += 512) ((short*)xh0)[idx] = 0;
    for (int idx = tid; idx < 2 * BC * X1STRIDE; idx += 512) ((short*)xh1)[idx] = 0;
#pragma unroll
    for (int f = 0; f < 16; ++f) {
        int ksm4 = f >> 2, g = f & 3;
        *(bs8*)&wlds[wv][ksm4][g][lane][0] =
            *(const bs8*)(wsw + W1BASE +
                (((wv * 4 + g) * 8 + (ksm4 + 4)) * 64 + lane) * 8);
    }
    __syncthreads();
    if (tid < 2 * BC) xh0[tid >> 4][tid & 15][INS] = (short)0x3f80;  // 1.0 bf16

    // ---- x(t) staging: 2 batch rows per wave, 28 active lanes per wave ----
    const int  xm = wv * 2 + (lane >> 5);   // batch row 0..15
    const int  xi = lane & 31;              // input feature
    const bool xldr = (xi < INS);
    const float* xp = xldr ? (x + ((size_t)(b0 + xm) * SEQ) * INS + xi) : x;
    float xv = xldr ? xp[0] : 0.f;

    float c0_0 = 0.f, c0_1 = 0.f, c0_2 = 0.f, c0_3 = 0.f;
    float c1_0 = 0.f, c1_1 = 0.f, c1_2 = 0.f, c1_3 = 0.f;
    const int aoff = quad * 8;

    // ---- MFMA macros; AF passed explicitly (af temps shared L1<->L0) ----
#define L1KR(ks, AF) { \
        acc1_0 = __builtin_amdgcn_mfma_f32_16x16x32_bf16(AF, w1_0_##ks, acc1_0, 0,0,0); \
        acc1_1 = __builtin_amdgcn_mfma_f32_16x16x32_bf16(AF, w1_1_##ks, acc1_1, 0,0,0); \
        acc1_2 = __builtin_amdgcn_mfma_f32_16x16x32_bf16(AF, w1_2_##ks, acc1_2, 0,0,0); \
        acc1_3 = __builtin_amdgcn_mfma_f32_16x16x32_bf16(AF, w1_3_##ks, acc1_3, 0,0,0); }
#define L1KL(ks, AF) { \
        const bs8 u0 = *(const bs8*)&wlds[wv][(ks)-4][0][lane][0]; \
        const bs8 u1 = *(const bs8*)&wlds[wv][(ks)-4][1][lane][0]; \
        const bs8 u2 = *(const bs8*)&wlds[wv][(ks)-4][2][lane][0]; \
        const bs8 u3 = *(const bs8*)&wlds[wv][(ks)-4][3][lane][0]; \
        acc1_0 = __builtin_amdgcn_mfma_f32_16x16x32_bf16(AF, u0, acc1_0, 0,0,0); \
        acc1_1 = __builtin_amdgcn_mfma_f32_16x16x32_bf16(AF, u1, acc1_1, 0,0,0); \
        acc1_2 = __builtin_amdgcn_mfma_f32_16x16x32_bf16(AF, u2, acc1_2, 0,0,0); \
        acc1_3 = __builtin_amdgcn_mfma_f32_16x16x32_bf16(AF, u3, acc1_3, 0,0,0); }
#define L0K(ks, AF) { \
        acc0_0 = __builtin_amdgcn_mfma_f32_16x16x32_bf16(AF, w0_0_##ks, acc0_0, 0,0,0); \
        acc0_1 = __builtin_amdgcn_mfma_f32_16x16x32_bf16(AF, w0_1_##ks, acc0_1, 0,0,0); \
        acc0_2 = __builtin_amdgcn_mfma_f32_16x16x32_bf16(AF, w0_2_##ks, acc0_2, 0,0,0); \
        acc0_3 = __builtin_amdgcn_mfma_f32_16x16x32_bf16(AF, w0_3_##ks, acc0_3, 0,0,0); }

    // ---- merged-denominator LSTM cell, gate constants pre-folded:
    //      acc already = preact * -log2e (i,f,o) or -2log2e (g) ----
#define CELLH(A0, A1, A2, A3, cvar, r, HOUT) { \
        float ei = __builtin_amdgcn_exp2f(A0[r]); \
        float ef = __builtin_amdgcn_exp2f(A1[r]); \
        float eg = __builtin_amdgcn_exp2f(A2[r]); \
        float eo = __builtin_amdgcn_exp2f(A3[r]); \
        float Di = 1.f + ei, Df = 1.f + ef, Dg = 1.f + eg, Do = 1.f + eo; \
        float rP = __builtin_amdgcn_rcpf(Df * Di * Dg); \
        float num = __builtin_fmaf(cvar * Di, Dg, (1.f - eg) * Df); \
        cvar = num * rP; \
        float ec = __builtin_amdgcn_exp2f(cvar * -2.88539008f); \
        float rQ = __builtin_amdgcn_rcpf((1.f + ec) * Do); \
        HOUT = (1.f - ec) * rQ; }

    // pack 2 h values (rows 2J, 2J+1 of this quad) with hw RNE, 2 b16 stores
#define STOREPAIR(HA, HB, J, ROW, COLOFF) { \
        unsigned pk; \
        asm("v_cvt_pk_bf16_f32 %0, %1, %2" : "=v"(pk) : "v"(HA), "v"(HB)); \
        xh1[ROW][quad * 4 + 2*(J)][(COLOFF) + u]     = (short)pk; \
        xh1[ROW][quad * 4 + 2*(J) + 1][(COLOFF) + u] = (short)(pk >> 16); }

#define CELL4_0(ROW) { \
        float h0_, h1_, h2_, h3_; \
        CELLH(acc0_0, acc0_1, acc0_2, acc0_3, c0_0, 0, h0_) \
        CELLH(acc0_0, acc0_1, acc0_2, acc0_3, c0_1, 1, h1_) \
        CELLH(acc0_0, acc0_1, acc0_2, acc0_3, c0_2, 2, h2_) \
        CELLH(acc0_0, acc0_1, acc0_2, acc0_3, c0_3, 3, h3_) \
        STOREPAIR(h0_, h1_, 0, ROW, 0) STOREPAIR(h2_, h3_, 1, ROW, 0) }

#define CELL1H(r, HOUT) CELLH(acc1_0, acc1_1, acc1_2, acc1_3, c1_##r, r, HOUT)

    // ---- prologue t=0: layer 0 only (h0(-1)=0 from zero-init) ----
    {
        const int p = 0, q = 1;
        if (xldr) xh0[p][xm][xi] = f2bf(xv);
        float xnext = xldr ? xp[INS] : 0.f;
        __syncthreads();
        const bs8 afx = *(const bs8*)&xh0[p][col][aoff];
        const bs8 af0 = *(const bs8*)&xh1[p][col][0 * 32 + aoff];
        const bs8 af1 = *(const bs8*)&xh1[p][col][1 * 32 + aoff];
        const bs8 af2 = *(const bs8*)&xh1[p][col][2 * 32 + aoff];
        const bs8 af3 = *(const bs8*)&xh1[p][col][3 * 32 + aoff];
        f4 acc0_0 = {0.f,0.f,0.f,0.f}, acc0_1 = {0.f,0.f,0.f,0.f};
        f4 acc0_2 = {0.f,0.f,0.f,0.f}, acc0_3 = {0.f,0.f,0.f,0.f};
        L0K(0, afx) L0K(1, af0) L0K(2, af1) L0K(3, af2) L0K(4, af3)
        CELL4_0(q)
        xv = xnext;
    }

    // ---- steady state: iter t does L1/CELL1 for t-1 and L0/CELL0 for t ----
    for (int t = 1; t < SEQ; ++t) {
        const int p = t & 1, q = p ^ 1;
        if (xldr) xh0[p][xm][xi] = f2bf(xv);
        float xnext = (xldr && (t + 1 < SEQ)) ? xp[(t + 1) * INS] : 0.f;
        __syncthreads();  // x(t), h0(t-1), h1(t-2) all visible in parity p

        // A-row burst: 9 ds_read_b128, loaded once, shared by L1 and L0
        const bs8 afx = *(const bs8*)&xh0[p][col][aoff];
        const bs8 af0 = *(const bs8*)&xh1[p][col][0 * 32 + aoff];
        const bs8 af1 = *(const bs8*)&xh1[p][col][1 * 32 + aoff];
        const bs8 af2 = *(const bs8*)&xh1[p][col][2 * 32 + aoff];
        const bs8 af3 = *(const bs8*)&xh1[p][col][3 * 32 + aoff];
        const bs8 af4 = *(const bs8*)&xh1[p][col][4 * 32 + aoff];
        const bs8 af5 = *(const bs8*)&xh1[p][col][5 * 32 + aoff];
        const bs8 af6 = *(const bs8*)&xh1[p][col][6 * 32 + aoff];
        const bs8 af7 = *(const bs8*)&xh1[p][col][7 * 32 + aoff];

        f4 acc1_0 = {b1_0, b1_0, b1_0, b1_0};
        f4 acc1_1 = {b1_1, b1_1, b1_1, b1_1};
        f4 acc1_2 = {b1_2, b1_2, b1_2, b1_2};
        f4 acc1_3 = {b1_3, b1_3, b1_3, b1_3};
        L1KR(0, af0) L1KR(1, af1) L1KR(2, af2) L1KR(3, af3)
        L1KL(4, af4) L1KL(5, af5) L1KL(6, af6) L1KL(7, af7)

        f4 acc0_0 = {0.f,0.f,0.f,0.f}, acc0_1 = {0.f,0.f,0.f,0.f};
        f4 acc0_2 = {0.f,0.f,0.f,0.f}, acc0_3 = {0.f,0.f,0.f,0.f};
        // interleave: matrix pipe (L0) and trans pipe (CELL1) concurrently
        float g0_, g1_, g2_, g3_;
        L0K(0, afx) CELL1H(0, g0_)
        L0K(1, af0) CELL1H(1, g1_)
        L0K(2, af1) CELL1H(2, g2_)
        L0K(3, af2) CELL1H(3, g3_)
        L0K(4, af3)
        STOREPAIR(g0_, g1_, 0, q, HID) STOREPAIR(g2_, g3_, 1, q, HID)
        CELL4_0(q)

        xv = xnext;
    }

    // ---- epilogue: L1/CELL1 for t = SEQ-1 (SEQ even -> parity 0) ----
    {
        const int p = 0, q = 1;
        __syncthreads();
        const bs8 af0 = *(const bs8*)&xh1[p][col][0 * 32 + aoff];
        const bs8 af1 = *(const bs8*)&xh1[p][col][1 * 32 + aoff];
        const bs8 af2 = *(const bs8*)&xh1[p][col][2 * 32 + aoff];
        const bs8 af3 = *(const bs8*)&xh1[p][col][3 * 32 + aoff];
        const bs8 af4 = *(const bs8*)&xh1[p][col][4 * 32 + aoff];
        const bs8 af5 = *(const bs8*)&xh1[p][col][5 * 32 + aoff];
        const bs8 af6 = *(const bs8*)&xh1[p][col][6 * 32 + aoff];
        const bs8 af7 = *(const bs8*)&xh1[p][col][7 * 32 + aoff];
        f4 acc1_0 = {b1_0, b1_0, b1_0, b1_0};
        f4 acc1_1 = {b1_1, b1_1, b1_1, b1_1};
        f4 acc1_2 = {b1_2, b1_2, b1_2, b1_2};
        f4 acc1_3 = {b1_3, b1_3, b1_3, b1_3};
        L1KR(0, af0) L1KR(1, af1) L1KR(2, af2) L1KR(3, af3)
        L1KL(4, af4) L1KL(5, af5) L1KL(6, af6) L1KL(7, af7)
        float g0_, g1_, g2_, g3_;
        CELL1H(0, g0_) CELL1H(1, g1_) CELL1H(2, g2_) CELL1H(3, g3_)
        STOREPAIR(g0_, g1_, 0, q, HID) STOREPAIR(g2_, g3_, 1, q, HID)
    }
    __syncthreads();

    // ---- final FC (128 -> 1) + sigmoid; h1(SEQ-1) lives in xh1[1][.][HID+..] ----
    if (tid < BC) {
        float s = bfc[0];
#pragma unroll 8
        for (int k2 = 0; k2 < HID; ++k2)
            s += bf2f(xh1[1][tid][HID + k2]) * Wfc[k2];
        out[b0 + tid] = sigm(s);
    }
}

extern "C" void kernel_launch(void* const* d_in, const int* in_sizes, int n_in,
                              void* d_out, int out_size, void* d_ws, size_t ws_size,
                              hipStream_t stream) {
    const float* x    = (const float*)d_in[0];
    const float* Wih0 = (const float*)d_in[1];
    const float* Whh0 = (const float*)d_in[2];
    const float* bih0 = (const float*)d_in[3];
    const float* bhh0 = (const float*)d_in[4];
    const float* Wih1 = (const float*)d_in[5];
    const float* Whh1 = (const float*)d_in[6];
    const float* bih1 = (const float*)d_in[7];
    const float* bhh1 = (const float*)d_in[8];
    const float* Wfc  = (const float*)d_in[9];
    const float* bfc  = (const float*)d_in[10];
    float* out = (float*)d_out;
    short* wsw = (short*)d_ws;   // 426 KB of bf16 fragment-ordered weights

    int nfrag = NFRAG0 + NFRAG1;
    lstm_prep<<<(nfrag + 255) / 256, 256, 0, stream>>>(Wih0, Whh0, bih0, bhh0,
                                                       Wih1, Whh1, wsw);
    dim3 grid(2048 / BC);   // 128 blocks, 1 per CU
    dim3 block(512);        // 8 waves; each wave owns 16 hidden units
    lstm_fused<<<grid, block, 0, stream>>>(x, Wfc, bfc, bih1, bhh1, wsw, out);
}

// Round 13
// 892.106 us; speedup vs baseline: 1.3469x; 1.0248x over previous
//
#include <hip/hip_runtime.h>
#include <hip/hip_bf16.h>

#define HID 128
#define SEQ 512
#define INS 14
#define BC 16
// K0 = 160 : [x(14) | 1 | pad->32 | h0(128)]   -> 5 k-steps of 32
// K1 = 256 : [h0(128) | h1(128)]               -> 8 k-steps of 32
#define X0STRIDE 40
#define X1STRIDE 264  // 256 + 8 pad shorts
#define NFRAG0 10240          // 8 waves * 4 gates * 5 ksteps * 64 lanes
#define NFRAG1 16384          // 8 waves * 4 gates * 8 ksteps * 64 lanes
#define W1BASE (NFRAG0 * 8)   // short offset of W1 region in ws

typedef __attribute__((ext_vector_type(8))) short bs8;
typedef __attribute__((ext_vector_type(4))) float f4;

__device__ __forceinline__ short f2bf(float f) {
    union { float f; unsigned u; } a; a.f = f;
    unsigned u = a.u;
    u += 0x7fffu + ((u >> 16) & 1u);   // RNE
    return (short)(u >> 16);
}
__device__ __forceinline__ float bf2f(short s) {
    union { unsigned u; float f; } a;
    a.u = ((unsigned)(unsigned short)s) << 16;
    return a.f;
}
__device__ __forceinline__ float sigm(float x) {
    return __builtin_amdgcn_rcpf(1.f + __builtin_amdgcn_exp2f(x * -1.44269504f));
}

// ---------------------------------------------------------------------------
// prep: swizzle weights into MFMA B-fragment order in ws (bf16 bits), with
// the exp2 gate constant FOLDED IN (r12): i,f,o rows scaled by -log2(e),
// tanh gate g rows by -2*log2(e). MFMA output = exp2 argument directly.
// ---------------------------------------------------------------------------
__global__ void lstm_prep(
    const float* __restrict__ Wih0, const float* __restrict__ Whh0,
    const float* __restrict__ bih0, const float* __restrict__ bhh0,
    const float* __restrict__ Wih1, const float* __restrict__ Whh1,
    short* __restrict__ wsw)
{
    int f = blockIdx.x * 256 + threadIdx.x;
    if (f >= NFRAG0 + NFRAG1) return;
    if (f < NFRAG0) {
        int lane = f & 63, t = f >> 6;
        int ks = t % 5, gw = t / 5, g = gw & 3, wv = gw >> 2;
        float sc = (g == 2) ? -2.88539008f : -1.44269504f;
        int row = g * HID + wv * 16 + (lane & 15);
        int kbase = ks * 32 + (lane >> 4) * 8;
        for (int j = 0; j < 8; ++j) {
            int k = kbase + j;
            float v;
            if (k < INS)        v = Wih0[row * INS + k];
            else if (k == INS)  v = bih0[row] + bhh0[row];
            else if (k < 32)    v = 0.f;
            else                v = Whh0[row * HID + (k - 32)];
            wsw[f * 8 + j] = f2bf(v * sc);
        }
    } else {
        int fl = f - NFRAG0;
        int lane = fl & 63, t = fl >> 6;
        int ks = t & 7, g = (t >> 3) & 3, wv = t >> 5;
        float sc = (g == 2) ? -2.88539008f : -1.44269504f;
        int row = g * HID + wv * 16 + (lane & 15);
        int kbase = ks * 32 + (lane >> 4) * 8;
        for (int j = 0; j < 8; ++j) {
            int k = kbase + j;
            float v = (k < HID) ? Wih1[row * HID + k] : Whh1[row * HID + (k - HID)];
            wsw[f * 8 + j] = f2bf(v * sc);
        }
    }
}

// ---------------------------------------------------------------------------
// main. Round-13 = round-12 (914 us) + CELL algebra trimming (the validated
// lever: VALU ops on the acc->exp dep path pay ~2x issue cost — r4/r7/r12):
//  (a) factor DiDg = Di*Dg: rP = rcp(DiDg*Df), num = fma(cs, DiDg, u)
//      — kills the cvar*Di mul;
//  (b) distribute-to-fma: (1-eg)*Df -> fma(-eg,mDf,mDf);
//      (1-ec)*rQ -> fma(-ec,rQ,rQ);
//  (c) SCALED CELL STATE cs = -2log2e * c: ec = exp2(cs) with no mul on
//      either the h-path or the c-recurrence; mDf = -2.885*Df feeds (b).
//  16 -> 13 VALU/cell-row (24 ops/thread/step) + shorter rP->h tail.
//  (d) x-loader RNE via v_cvt_pk_bf16_f32 (4 ops -> 1).
// Closed branches (r5-r11 counter evidence): de-phase, 4w/SIMD role-split,
// swizzle, chain-split, cross-CU ring, reg/LDS rebalance. 36 reg-frags +
// 16 LDS-frags is capacity-optimal at 2 waves/SIMD.
// Canaries: absmax <= 0.00390625 (else revert to r12); WRITE_SIZE ~8 B.
// ---------------------------------------------------------------------------
__global__ __attribute__((amdgpu_flat_work_group_size(512, 512)))
__attribute__((amdgpu_waves_per_eu(2, 2))) void lstm_fused(
    const float* __restrict__ x,
    const float* __restrict__ Wfc,  const float* __restrict__ bfc,
    const float* __restrict__ bih1, const float* __restrict__ bhh1,
    const short* __restrict__ wsw,
    float* __restrict__ out)
{
    __shared__ __align__(16) short xh0[2][BC][X0STRIDE];
    __shared__ __align__(16) short xh1[2][BC][X1STRIDE];
    // L1 ks4-7 weights: [wv][ks-4][gate][lane][8] -> 128 KB, per-wave private
    __shared__ __align__(16) short wlds[8][4][4][64][8];

    const int tid  = threadIdx.x;
    const int lane = tid & 63;
    const int wv   = tid >> 6;      // 0..7
    const int col  = lane & 15;
    const int quad = lane >> 4;
    const int u    = wv * 16 + col; // hidden unit owned by this lane
    const int b0   = blockIdx.x * BC;

    // ---- register-resident weight fragments: L0 all 20, L1 ks0-3 (16) ----
    const short* wb0 = wsw + ((wv * 20) * 64 + lane) * 8;           // wv*4*5
    const short* wb1 = wsw + W1BASE + ((wv * 32) * 64 + lane) * 8;  // wv*4*8
#define DW0(g,ks) const bs8 w0_##g##_##ks = *(const bs8*)(wb0 + ((g)*5+(ks))*512);
#define DW1(g,ks) const bs8 w1_##g##_##ks = *(const bs8*)(wb1 + ((g)*8+(ks))*512);
    DW0(0,0) DW0(0,1) DW0(0,2) DW0(0,3) DW0(0,4)
    DW0(1,0) DW0(1,1) DW0(1,2) DW0(1,3) DW0(1,4)
    DW0(2,0) DW0(2,1) DW0(2,2) DW0(2,3) DW0(2,4)
    DW0(3,0) DW0(3,1) DW0(3,2) DW0(3,3) DW0(3,4)
    DW1(0,0) DW1(0,1) DW1(0,2) DW1(0,3)
    DW1(1,0) DW1(1,1) DW1(1,2) DW1(1,3)
    DW1(2,0) DW1(2,1) DW1(2,2) DW1(2,3)
    DW1(3,0) DW1(3,1) DW1(3,2) DW1(3,3)

    // biases pre-scaled by the same gate constants as the weights (r12)
    const float b1_0 = (bih1[0 * HID + u] + bhh1[0 * HID + u]) * -1.44269504f;
    const float b1_1 = (bih1[1 * HID + u] + bhh1[1 * HID + u]) * -1.44269504f;
    const float b1_2 = (bih1[2 * HID + u] + bhh1[2 * HID + u]) * -2.88539008f;
    const float b1_3 = (bih1[3 * HID + u] + bhh1[3 * HID + u]) * -1.44269504f;

    // ---- LDS init: zeros + constant-1 bias column + L1 ks4-7 weight tiles ----
    for (int idx = tid; idx < 2 * BC * X0STRIDE; idx += 512) ((short*)xh0)[idx] = 0;
    for (int idx = tid; idx < 2 * BC * X1STRIDE; idx += 512) ((short*)xh1)[idx] = 0;
#pragma unroll
    for (int f = 0; f < 16; ++f) {
        int ksm4 = f >> 2, g = f & 3;
        *(bs8*)&wlds[wv][ksm4][g][lane][0] =
            *(const bs8*)(wsw + W1BASE +
                (((wv * 4 + g) * 8 + (ksm4 + 4)) * 64 + lane) * 8);
    }
    __syncthreads();
    if (tid < 2 * BC) xh0[tid >> 4][tid & 15][INS] = (short)0x3f80;  // 1.0 bf16

    // ---- x(t) staging: 2 batch rows per wave, 28 active lanes per wave ----
    const int  xm = wv * 2 + (lane >> 5);   // batch row 0..15
    const int  xi = lane & 31;              // input feature
    const bool xldr = (xi < INS);
    const float* xp = xldr ? (x + ((size_t)(b0 + xm) * SEQ) * INS + xi) : x;
    float xv = xldr ? xp[0] : 0.f;

    // cell state tracked SCALED: cs = -2*log2(e) * c  (init c=0 -> cs=0)
    float c0_0 = 0.f, c0_1 = 0.f, c0_2 = 0.f, c0_3 = 0.f;
    float c1_0 = 0.f, c1_1 = 0.f, c1_2 = 0.f, c1_3 = 0.f;
    const int aoff = quad * 8;

    // ---- MFMA macros; AF passed explicitly (af temps shared L1<->L0) ----
#define L1KR(ks, AF) { \
        acc1_0 = __builtin_amdgcn_mfma_f32_16x16x32_bf16(AF, w1_0_##ks, acc1_0, 0,0,0); \
        acc1_1 = __builtin_amdgcn_mfma_f32_16x16x32_bf16(AF, w1_1_##ks, acc1_1, 0,0,0); \
        acc1_2 = __builtin_amdgcn_mfma_f32_16x16x32_bf16(AF, w1_2_##ks, acc1_2, 0,0,0); \
        acc1_3 = __builtin_amdgcn_mfma_f32_16x16x32_bf16(AF, w1_3_##ks, acc1_3, 0,0,0); }
#define L1KL(ks, AF) { \
        const bs8 u0 = *(const bs8*)&wlds[wv][(ks)-4][0][lane][0]; \
        const bs8 u1 = *(const bs8*)&wlds[wv][(ks)-4][1][lane][0]; \
        const bs8 u2 = *(const bs8*)&wlds[wv][(ks)-4][2][lane][0]; \
        const bs8 u3 = *(const bs8*)&wlds[wv][(ks)-4][3][lane][0]; \
        acc1_0 = __builtin_amdgcn_mfma_f32_16x16x32_bf16(AF, u0, acc1_0, 0,0,0); \
        acc1_1 = __builtin_amdgcn_mfma_f32_16x16x32_bf16(AF, u1, acc1_1, 0,0,0); \
        acc1_2 = __builtin_amdgcn_mfma_f32_16x16x32_bf16(AF, u2, acc1_2, 0,0,0); \
        acc1_3 = __builtin_amdgcn_mfma_f32_16x16x32_bf16(AF, u3, acc1_3, 0,0,0); }
#define L0K(ks, AF) { \
        acc0_0 = __builtin_amdgcn_mfma_f32_16x16x32_bf16(AF, w0_0_##ks, acc0_0, 0,0,0); \
        acc0_1 = __builtin_amdgcn_mfma_f32_16x16x32_bf16(AF, w0_1_##ks, acc0_1, 0,0,0); \
        acc0_2 = __builtin_amdgcn_mfma_f32_16x16x32_bf16(AF, w0_2_##ks, acc0_2, 0,0,0); \
        acc0_3 = __builtin_amdgcn_mfma_f32_16x16x32_bf16(AF, w0_3_##ks, acc0_3, 0,0,0); }

    // ---- trimmed merged-denominator cell, scaled-c form ----
    // acc already = preact * -log2e (i,f,o) or -2log2e (g);
    // cvar holds cs = -2log2e * c.
    //   c' = [c*Di*Dg + (1-eg)*Df] / (Df*Di*Dg)
    //   cs' = [cs*DiDg + K*(1-eg)*Df] * rP,  K = -2log2e
    //   mDf = K*Df;  u = mDf - eg*mDf = fma(-eg, mDf, mDf)
    //   tanh(c') = (1-ec)/(1+ec),  ec = exp2(cs')   <- no mul
    //   h = fma(-ec, rQ, rQ),  rQ = rcp((1+ec)*Do)
#define CELLH(A0, A1, A2, A3, cvar, r, HOUT) { \
        float ei = __builtin_amdgcn_exp2f(A0[r]); \
        float ef = __builtin_amdgcn_exp2f(A1[r]); \
        float eg = __builtin_amdgcn_exp2f(A2[r]); \
        float eo = __builtin_amdgcn_exp2f(A3[r]); \
        float Di = 1.f + ei, Df = 1.f + ef, Dg = 1.f + eg, Do = 1.f + eo; \
        float DiDg = Di * Dg; \
        float rP = __builtin_amdgcn_rcpf(DiDg * Df); \
        float mDf = Df * -2.88539008f; \
        float uu = __builtin_fmaf(-eg, mDf, mDf); \
        cvar = __builtin_fmaf(cvar, DiDg, uu) * rP; \
        float ec = __builtin_amdgcn_exp2f(cvar); \
        float rQ = __builtin_amdgcn_rcpf((1.f + ec) * Do); \
        HOUT = __builtin_fmaf(-ec, rQ, rQ); }

    // pack 2 h values (rows 2J, 2J+1 of this quad) with hw RNE, 2 b16 stores
#define STOREPAIR(HA, HB, J, ROW, COLOFF) { \
        unsigned pk; \
        asm("v_cvt_pk_bf16_f32 %0, %1, %2" : "=v"(pk) : "v"(HA), "v"(HB)); \
        xh1[ROW][quad * 4 + 2*(J)][(COLOFF) + u]     = (short)pk; \
        xh1[ROW][quad * 4 + 2*(J) + 1][(COLOFF) + u] = (short)(pk >> 16); }

    // x-store with hw RNE (1 cvt instead of 4-op manual round)
#define XSTORE(P) { \
        unsigned xpk; \
        asm("v_cvt_pk_bf16_f32 %0, %1, %2" : "=v"(xpk) : "v"(xv), "v"(xv)); \
        xh0[P][xm][xi] = (short)xpk; }

#define CELL4_0(ROW) { \
        float h0_, h1_, h2_, h3_; \
        CELLH(acc0_0, acc0_1, acc0_2, acc0_3, c0_0, 0, h0_) \
        CELLH(acc0_0, acc0_1, acc0_2, acc0_3, c0_1, 1, h1_) \
        CELLH(acc0_0, acc0_1, acc0_2, acc0_3, c0_2, 2, h2_) \
        CELLH(acc0_0, acc0_1, acc0_2, acc0_3, c0_3, 3, h3_) \
        STOREPAIR(h0_, h1_, 0, ROW, 0) STOREPAIR(h2_, h3_, 1, ROW, 0) }

#define CELL1H(r, HOUT) CELLH(acc1_0, acc1_1, acc1_2, acc1_3, c1_##r, r, HOUT)

    // ---- prologue t=0: layer 0 only (h0(-1)=0 from zero-init) ----
    {
        const int p = 0, q = 1;
        if (xldr) XSTORE(p)
        float xnext = xldr ? xp[INS] : 0.f;
        __syncthreads();
        const bs8 afx = *(const bs8*)&xh0[p][col][aoff];
        const bs8 af0 = *(const bs8*)&xh1[p][col][0 * 32 + aoff];
        const bs8 af1 = *(const bs8*)&xh1[p][col][1 * 32 + aoff];
        const bs8 af2 = *(const bs8*)&xh1[p][col][2 * 32 + aoff];
        const bs8 af3 = *(const bs8*)&xh1[p][col][3 * 32 + aoff];
        f4 acc0_0 = {0.f,0.f,0.f,0.f}, acc0_1 = {0.f,0.f,0.f,0.f};
        f4 acc0_2 = {0.f,0.f,0.f,0.f}, acc0_3 = {0.f,0.f,0.f,0.f};
        L0K(0, afx) L0K(1, af0) L0K(2, af1) L0K(3, af2) L0K(4, af3)
        CELL4_0(q)
        xv = xnext;
    }

    // ---- steady state: iter t does L1/CELL1 for t-1 and L0/CELL0 for t ----
    for (int t = 1; t < SEQ; ++t) {
        const int p = t & 1, q = p ^ 1;
        if (xldr) XSTORE(p)
        float xnext = (xldr && (t + 1 < SEQ)) ? xp[(t + 1) * INS] : 0.f;
        __syncthreads();  // x(t), h0(t-1), h1(t-2) all visible in parity p

        // A-row burst: 9 ds_read_b128, loaded once, shared by L1 and L0
        const bs8 afx = *(const bs8*)&xh0[p][col][aoff];
        const bs8 af0 = *(const bs8*)&xh1[p][col][0 * 32 + aoff];
        const bs8 af1 = *(const bs8*)&xh1[p][col][1 * 32 + aoff];
        const bs8 af2 = *(const bs8*)&xh1[p][col][2 * 32 + aoff];
        const bs8 af3 = *(const bs8*)&xh1[p][col][3 * 32 + aoff];
        const bs8 af4 = *(const bs8*)&xh1[p][col][4 * 32 + aoff];
        const bs8 af5 = *(const bs8*)&xh1[p][col][5 * 32 + aoff];
        const bs8 af6 = *(const bs8*)&xh1[p][col][6 * 32 + aoff];
        const bs8 af7 = *(const bs8*)&xh1[p][col][7 * 32 + aoff];

        f4 acc1_0 = {b1_0, b1_0, b1_0, b1_0};
        f4 acc1_1 = {b1_1, b1_1, b1_1, b1_1};
        f4 acc1_2 = {b1_2, b1_2, b1_2, b1_2};
        f4 acc1_3 = {b1_3, b1_3, b1_3, b1_3};
        L1KR(0, af0) L1KR(1, af1) L1KR(2, af2) L1KR(3, af3)
        L1KL(4, af4) L1KL(5, af5) L1KL(6, af6) L1KL(7, af7)

        f4 acc0_0 = {0.f,0.f,0.f,0.f}, acc0_1 = {0.f,0.f,0.f,0.f};
        f4 acc0_2 = {0.f,0.f,0.f,0.f}, acc0_3 = {0.f,0.f,0.f,0.f};
        // interleave: matrix pipe (L0) and trans pipe (CELL1) concurrently
        float g0_, g1_, g2_, g3_;
        L0K(0, afx) CELL1H(0, g0_)
        L0K(1, af0) CELL1H(1, g1_)
        L0K(2, af1) CELL1H(2, g2_)
        L0K(3, af2) CELL1H(3, g3_)
        L0K(4, af3)
        STOREPAIR(g0_, g1_, 0, q, HID) STOREPAIR(g2_, g3_, 1, q, HID)
        CELL4_0(q)

        xv = xnext;
    }

    // ---- epilogue: L1/CELL1 for t = SEQ-1 (SEQ even -> parity 0) ----
    {
        const int p = 0, q = 1;
        __syncthreads();
        const bs8 af0 = *(const bs8*)&xh1[p][col][0 * 32 + aoff];
        const bs8 af1 = *(const bs8*)&xh1[p][col][1 * 32 + aoff];
        const bs8 af2 = *(const bs8*)&xh1[p][col][2 * 32 + aoff];
        const bs8 af3 = *(const bs8*)&xh1[p][col][3 * 32 + aoff];
        const bs8 af4 = *(const bs8*)&xh1[p][col][4 * 32 + aoff];
        const bs8 af5 = *(const bs8*)&xh1[p][col][5 * 32 + aoff];
        const bs8 af6 = *(const bs8*)&xh1[p][col][6 * 32 + aoff];
        const bs8 af7 = *(const bs8*)&xh1[p][col][7 * 32 + aoff];
        f4 acc1_0 = {b1_0, b1_0, b1_0, b1_0};
        f4 acc1_1 = {b1_1, b1_1, b1_1, b1_1};
        f4 acc1_2 = {b1_2, b1_2, b1_2, b1_2};
        f4 acc1_3 = {b1_3, b1_3, b1_3, b1_3};
        L1KR(0, af0) L1KR(1, af1) L1KR(2, af2) L1KR(3, af3)
        L1KL(4, af4) L1KL(5, af5) L1KL(6, af6) L1KL(7, af7)
        float g0_, g1_, g2_, g3_;
        CELL1H(0, g0_) CELL1H(1, g1_) CELL1H(2, g2_) CELL1H(3, g3_)
        STOREPAIR(g0_, g1_, 0, q, HID) STOREPAIR(g2_, g3_, 1, q, HID)
    }
    __syncthreads();

    // ---- final FC (128 -> 1) + sigmoid; h1(SEQ-1) lives in xh1[1][.][HID+..] ----
    if (tid < BC) {
        float s = bfc[0];
#pragma unroll 8
        for (int k2 = 0; k2 < HID; ++k2)
            s += bf2f(xh1[1][tid][HID + k2]) * Wfc[k2];
        out[b0 + tid] = sigm(s);
    }
}

extern "C" void kernel_launch(void* const* d_in, const int* in_sizes, int n_in,
                              void* d_out, int out_size, void* d_ws, size_t ws_size,
                              hipStream_t stream) {
    const float* x    = (const float*)d_in[0];
    const float* Wih0 = (const float*)d_in[1];
    const float* Whh0 = (const float*)d_in[2];
    const float* bih0 = (const float*)d_in[3];
    const float* bhh0 = (const float*)d_in[4];
    const float* Wih1 = (const float*)d_in[5];
    const float* Whh1 = (const float*)d_in[6];
    const float* bih1 = (const float*)d_in[7];
    const float* bhh1 = (const float*)d_in[8];
    const float* Wfc  = (const float*)d_in[9];
    const float* bfc  = (const float*)d_in[10];
    float* out = (float*)d_out;
    short* wsw = (short*)d_ws;   // 426 KB of bf16 fragment-ordered weights

    int nfrag = NFRAG0 + NFRAG1;
    lstm_prep<<<(nfrag + 255) / 256, 256, 0, stream>>>(Wih0, Whh0, bih0, bhh0,
                                                       Wih1, Whh1, wsw);
    dim3 grid(2048 / BC);   // 128 blocks, 1 per CU
    dim3 block(512);        // 8 waves; each wave owns 16 hidden units
    lstm_fused<<<grid, block, 0, stream>>>(x, Wfc, bfc, bih1, bhh1, wsw, out);
}

// Round 14
// 867.144 us; speedup vs baseline: 1.3857x; 1.0288x over previous
//
#include <hip/hip_runtime.h>
#include <hip/hip_bf16.h>

#define HID 128
#define SEQ 512
#define INS 14
#define BC 16
// K0 = 160 : [x(14) | 1 | pad->32 | h0(128)]   -> 5 k-steps of 32
// K1 = 256 : [h0(128) | h1(128)]               -> 8 k-steps of 32
#define X0STRIDE 40
#define X1STRIDE 264  // 256 + 8 pad shorts
#define NFRAG0 10240          // 8 waves * 4 gates * 5 ksteps * 64 lanes
#define NFRAG1 16384          // 8 waves * 4 gates * 8 ksteps * 64 lanes
#define W1BASE (NFRAG0 * 8)   // short offset of W1 region in ws

typedef __attribute__((ext_vector_type(8))) short bs8;
typedef __attribute__((ext_vector_type(4))) float f4;

__device__ __forceinline__ short f2bf(float f) {
    union { float f; unsigned u; } a; a.f = f;
    unsigned u = a.u;
    u += 0x7fffu + ((u >> 16) & 1u);   // RNE
    return (short)(u >> 16);
}
__device__ __forceinline__ float bf2f(short s) {
    union { unsigned u; float f; } a;
    a.u = ((unsigned)(unsigned short)s) << 16;
    return a.f;
}
__device__ __forceinline__ float sigm(float x) {
    return __builtin_amdgcn_rcpf(1.f + __builtin_amdgcn_exp2f(x * -1.44269504f));
}

// ---------------------------------------------------------------------------
// prep: swizzle weights into MFMA B-fragment order in ws (bf16 bits), with
// the exp2 gate constant FOLDED IN (r12): i,f,o rows scaled by -log2(e),
// tanh gate g rows by -2*log2(e). MFMA output = exp2 argument directly.
// ---------------------------------------------------------------------------
__global__ void lstm_prep(
    const float* __restrict__ Wih0, const float* __restrict__ Whh0,
    const float* __restrict__ bih0, const float* __restrict__ bhh0,
    const float* __restrict__ Wih1, const float* __restrict__ Whh1,
    short* __restrict__ wsw)
{
    int f = blockIdx.x * 256 + threadIdx.x;
    if (f >= NFRAG0 + NFRAG1) return;
    if (f < NFRAG0) {
        int lane = f & 63, t = f >> 6;
        int ks = t % 5, gw = t / 5, g = gw & 3, wv = gw >> 2;
        float sc = (g == 2) ? -2.88539008f : -1.44269504f;
        int row = g * HID + wv * 16 + (lane & 15);
        int kbase = ks * 32 + (lane >> 4) * 8;
        for (int j = 0; j < 8; ++j) {
            int k = kbase + j;
            float v;
            if (k < INS)        v = Wih0[row * INS + k];
            else if (k == INS)  v = bih0[row] + bhh0[row];
            else if (k < 32)    v = 0.f;
            else                v = Whh0[row * HID + (k - 32)];
            wsw[f * 8 + j] = f2bf(v * sc);
        }
    } else {
        int fl = f - NFRAG0;
        int lane = fl & 63, t = fl >> 6;
        int ks = t & 7, g = (t >> 3) & 3, wv = t >> 5;
        float sc = (g == 2) ? -2.88539008f : -1.44269504f;
        int row = g * HID + wv * 16 + (lane & 15);
        int kbase = ks * 32 + (lane >> 4) * 8;
        for (int j = 0; j < 8; ++j) {
            int k = kbase + j;
            float v = (k < HID) ? Wih1[row * HID + k] : Whh1[row * HID + (k - HID)];
            wsw[f * 8 + j] = f2bf(v * sc);
        }
    }
}

// ---------------------------------------------------------------------------
// main. Round-14 = round-13 (steady 866 us) + MANUAL 2-STEP UNROLL of the
// steady-state loop with LITERAL parity p/q: all 9 af-read and 10 store
// addresses const-fold into ds instruction offsets (~25-35 VALU/step of
// parity/addr/loop arithmetic removed), loop control halves, and the
// scheduler gets a seam (body-2 x-store under body-1 CELL0 tail).
// Zero numeric change; zero liveness change. 511 steady iters = single
// t=1 body + 255 literal (p=0,q=1)(p=1,q=0) pairs.
// Validated lever history: r4/r7/r12/r13 (dep-path VALU trims) all paid;
// structural levers (r5 de-phase, r6 role-split, r8 swizzle, r9 chain
// split, r10 cross-CU ring, r11 reg/LDS rebalance) all falsified.
// Canaries: absmax == 0.00390625 exactly; WRITE_SIZE ~8 B.
// ---------------------------------------------------------------------------
__global__ __attribute__((amdgpu_flat_work_group_size(512, 512)))
__attribute__((amdgpu_waves_per_eu(2, 2))) void lstm_fused(
    const float* __restrict__ x,
    const float* __restrict__ Wfc,  const float* __restrict__ bfc,
    const float* __restrict__ bih1, const float* __restrict__ bhh1,
    const short* __restrict__ wsw,
    float* __restrict__ out)
{
    __shared__ __align__(16) short xh0[2][BC][X0STRIDE];
    __shared__ __align__(16) short xh1[2][BC][X1STRIDE];
    // L1 ks4-7 weights: [wv][ks-4][gate][lane][8] -> 128 KB, per-wave private
    __shared__ __align__(16) short wlds[8][4][4][64][8];

    const int tid  = threadIdx.x;
    const int lane = tid & 63;
    const int wv   = tid >> 6;      // 0..7
    const int col  = lane & 15;
    const int quad = lane >> 4;
    const int u    = wv * 16 + col; // hidden unit owned by this lane
    const int b0   = blockIdx.x * BC;

    // ---- register-resident weight fragments: L0 all 20, L1 ks0-3 (16) ----
    const short* wb0 = wsw + ((wv * 20) * 64 + lane) * 8;           // wv*4*5
    const short* wb1 = wsw + W1BASE + ((wv * 32) * 64 + lane) * 8;  // wv*4*8
#define DW0(g,ks) const bs8 w0_##g##_##ks = *(const bs8*)(wb0 + ((g)*5+(ks))*512);
#define DW1(g,ks) const bs8 w1_##g##_##ks = *(const bs8*)(wb1 + ((g)*8+(ks))*512);
    DW0(0,0) DW0(0,1) DW0(0,2) DW0(0,3) DW0(0,4)
    DW0(1,0) DW0(1,1) DW0(1,2) DW0(1,3) DW0(1,4)
    DW0(2,0) DW0(2,1) DW0(2,2) DW0(2,3) DW0(2,4)
    DW0(3,0) DW0(3,1) DW0(3,2) DW0(3,3) DW0(3,4)
    DW1(0,0) DW1(0,1) DW1(0,2) DW1(0,3)
    DW1(1,0) DW1(1,1) DW1(1,2) DW1(1,3)
    DW1(2,0) DW1(2,1) DW1(2,2) DW1(2,3)
    DW1(3,0) DW1(3,1) DW1(3,2) DW1(3,3)

    // biases pre-scaled by the same gate constants as the weights (r12)
    const float b1_0 = (bih1[0 * HID + u] + bhh1[0 * HID + u]) * -1.44269504f;
    const float b1_1 = (bih1[1 * HID + u] + bhh1[1 * HID + u]) * -1.44269504f;
    const float b1_2 = (bih1[2 * HID + u] + bhh1[2 * HID + u]) * -2.88539008f;
    const float b1_3 = (bih1[3 * HID + u] + bhh1[3 * HID + u]) * -1.44269504f;

    // ---- LDS init: zeros + constant-1 bias column + L1 ks4-7 weight tiles ----
    for (int idx = tid; idx < 2 * BC * X0STRIDE; idx += 512) ((short*)xh0)[idx] = 0;
    for (int idx = tid; idx < 2 * BC * X1STRIDE; idx += 512) ((short*)xh1)[idx] = 0;
#pragma unroll
    for (int f = 0; f < 16; ++f) {
        int ksm4 = f >> 2, g = f & 3;
        *(bs8*)&wlds[wv][ksm4][g][lane][0] =
            *(const bs8*)(wsw + W1BASE +
                (((wv * 4 + g) * 8 + (ksm4 + 4)) * 64 + lane) * 8);
    }
    __syncthreads();
    if (tid < 2 * BC) xh0[tid >> 4][tid & 15][INS] = (short)0x3f80;  // 1.0 bf16
    // note: the bias column must be bf16(1.0); the k=14 weight column was
    // pre-scaled, so W*1 carries the scaled bias — unchanged from r12/r13.

    // ---- x(t) staging: 2 batch rows per wave, 28 active lanes per wave ----
    const int  xm = wv * 2 + (lane >> 5);   // batch row 0..15
    const int  xi = lane & 31;              // input feature
    const bool xldr = (xi < INS);
    const float* xp = xldr ? (x + ((size_t)(b0 + xm) * SEQ) * INS + xi) : x;
    float xv = xldr ? xp[0] : 0.f;

    // cell state tracked SCALED: cs = -2*log2(e) * c  (init c=0 -> cs=0)
    float c0_0 = 0.f, c0_1 = 0.f, c0_2 = 0.f, c0_3 = 0.f;
    float c1_0 = 0.f, c1_1 = 0.f, c1_2 = 0.f, c1_3 = 0.f;
    const int aoff = quad * 8;

    // ---- MFMA macros; AF passed explicitly (af temps shared L1<->L0) ----
#define L1KR(ks, AF) { \
        acc1_0 = __builtin_amdgcn_mfma_f32_16x16x32_bf16(AF, w1_0_##ks, acc1_0, 0,0,0); \
        acc1_1 = __builtin_amdgcn_mfma_f32_16x16x32_bf16(AF, w1_1_##ks, acc1_1, 0,0,0); \
        acc1_2 = __builtin_amdgcn_mfma_f32_16x16x32_bf16(AF, w1_2_##ks, acc1_2, 0,0,0); \
        acc1_3 = __builtin_amdgcn_mfma_f32_16x16x32_bf16(AF, w1_3_##ks, acc1_3, 0,0,0); }
#define L1KL(ks, AF) { \
        const bs8 u0 = *(const bs8*)&wlds[wv][(ks)-4][0][lane][0]; \
        const bs8 u1 = *(const bs8*)&wlds[wv][(ks)-4][1][lane][0]; \
        const bs8 u2 = *(const bs8*)&wlds[wv][(ks)-4][2][lane][0]; \
        const bs8 u3 = *(const bs8*)&wlds[wv][(ks)-4][3][lane][0]; \
        acc1_0 = __builtin_amdgcn_mfma_f32_16x16x32_bf16(AF, u0, acc1_0, 0,0,0); \
        acc1_1 = __builtin_amdgcn_mfma_f32_16x16x32_bf16(AF, u1, acc1_1, 0,0,0); \
        acc1_2 = __builtin_amdgcn_mfma_f32_16x16x32_bf16(AF, u2, acc1_2, 0,0,0); \
        acc1_3 = __builtin_amdgcn_mfma_f32_16x16x32_bf16(AF, u3, acc1_3, 0,0,0); }
#define L0K(ks, AF) { \
        acc0_0 = __builtin_amdgcn_mfma_f32_16x16x32_bf16(AF, w0_0_##ks, acc0_0, 0,0,0); \
        acc0_1 = __builtin_amdgcn_mfma_f32_16x16x32_bf16(AF, w0_1_##ks, acc0_1, 0,0,0); \
        acc0_2 = __builtin_amdgcn_mfma_f32_16x16x32_bf16(AF, w0_2_##ks, acc0_2, 0,0,0); \
        acc0_3 = __builtin_amdgcn_mfma_f32_16x16x32_bf16(AF, w0_3_##ks, acc0_3, 0,0,0); }

    // ---- trimmed merged-denominator cell, scaled-c form (r13) ----
#define CELLH(A0, A1, A2, A3, cvar, r, HOUT) { \
        float ei = __builtin_amdgcn_exp2f(A0[r]); \
        float ef = __builtin_amdgcn_exp2f(A1[r]); \
        float eg = __builtin_amdgcn_exp2f(A2[r]); \
        float eo = __builtin_amdgcn_exp2f(A3[r]); \
        float Di = 1.f + ei, Df = 1.f + ef, Dg = 1.f + eg, Do = 1.f + eo; \
        float DiDg = Di * Dg; \
        float rP = __builtin_amdgcn_rcpf(DiDg * Df); \
        float mDf = Df * -2.88539008f; \
        float uu = __builtin_fmaf(-eg, mDf, mDf); \
        cvar = __builtin_fmaf(cvar, DiDg, uu) * rP; \
        float ec = __builtin_amdgcn_exp2f(cvar); \
        float rQ = __builtin_amdgcn_rcpf((1.f + ec) * Do); \
        HOUT = __builtin_fmaf(-ec, rQ, rQ); }

    // pack 2 h values (rows 2J, 2J+1 of this quad) with hw RNE, 2 b16 stores
#define STOREPAIR(HA, HB, J, ROW, COLOFF) { \
        unsigned pk; \
        asm("v_cvt_pk_bf16_f32 %0, %1, %2" : "=v"(pk) : "v"(HA), "v"(HB)); \
        xh1[ROW][quad * 4 + 2*(J)][(COLOFF) + u]     = (short)pk; \
        xh1[ROW][quad * 4 + 2*(J) + 1][(COLOFF) + u] = (short)(pk >> 16); }

    // x-store with hw RNE (1 cvt instead of 4-op manual round)
#define XSTORE(P) { \
        unsigned xpk; \
        asm("v_cvt_pk_bf16_f32 %0, %1, %2" : "=v"(xpk) : "v"(xv), "v"(xv)); \
        xh0[P][xm][xi] = (short)xpk; }

#define CELL4_0(ROW) { \
        float h0_, h1_, h2_, h3_; \
        CELLH(acc0_0, acc0_1, acc0_2, acc0_3, c0_0, 0, h0_) \
        CELLH(acc0_0, acc0_1, acc0_2, acc0_3, c0_1, 1, h1_) \
        CELLH(acc0_0, acc0_1, acc0_2, acc0_3, c0_2, 2, h2_) \
        CELLH(acc0_0, acc0_1, acc0_2, acc0_3, c0_3, 3, h3_) \
        STOREPAIR(h0_, h1_, 0, ROW, 0) STOREPAIR(h2_, h3_, 1, ROW, 0) }

#define CELL1H(r, HOUT) CELLH(acc1_0, acc1_1, acc1_2, acc1_3, c1_##r, r, HOUT)

    // ---- full steady-state body with LITERAL parity P/Q and step TT ----
#define STEP(P, Q, TT) { \
        if (xldr) XSTORE(P) \
        float xnext = (xldr && ((TT) + 1 < SEQ)) ? xp[((TT) + 1) * INS] : 0.f; \
        __syncthreads(); \
        const bs8 afx = *(const bs8*)&xh0[P][col][aoff]; \
        const bs8 af0 = *(const bs8*)&xh1[P][col][0 * 32 + aoff]; \
        const bs8 af1 = *(const bs8*)&xh1[P][col][1 * 32 + aoff]; \
        const bs8 af2 = *(const bs8*)&xh1[P][col][2 * 32 + aoff]; \
        const bs8 af3 = *(const bs8*)&xh1[P][col][3 * 32 + aoff]; \
        const bs8 af4 = *(const bs8*)&xh1[P][col][4 * 32 + aoff]; \
        const bs8 af5 = *(const bs8*)&xh1[P][col][5 * 32 + aoff]; \
        const bs8 af6 = *(const bs8*)&xh1[P][col][6 * 32 + aoff]; \
        const bs8 af7 = *(const bs8*)&xh1[P][col][7 * 32 + aoff]; \
        f4 acc1_0 = {b1_0, b1_0, b1_0, b1_0}; \
        f4 acc1_1 = {b1_1, b1_1, b1_1, b1_1}; \
        f4 acc1_2 = {b1_2, b1_2, b1_2, b1_2}; \
        f4 acc1_3 = {b1_3, b1_3, b1_3, b1_3}; \
        L1KR(0, af0) L1KR(1, af1) L1KR(2, af2) L1KR(3, af3) \
        L1KL(4, af4) L1KL(5, af5) L1KL(6, af6) L1KL(7, af7) \
        f4 acc0_0 = {0.f,0.f,0.f,0.f}, acc0_1 = {0.f,0.f,0.f,0.f}; \
        f4 acc0_2 = {0.f,0.f,0.f,0.f}, acc0_3 = {0.f,0.f,0.f,0.f}; \
        float g0_, g1_, g2_, g3_; \
        L0K(0, afx) CELL1H(0, g0_) \
        L0K(1, af0) CELL1H(1, g1_) \
        L0K(2, af1) CELL1H(2, g2_) \
        L0K(3, af2) CELL1H(3, g3_) \
        L0K(4, af3) \
        STOREPAIR(g0_, g1_, 0, Q, HID) STOREPAIR(g2_, g3_, 1, Q, HID) \
        CELL4_0(Q) \
        xv = xnext; }

    // ---- prologue t=0: layer 0 only (h0(-1)=0 from zero-init) ----
    {
        if (xldr) XSTORE(0)
        float xnext = xldr ? xp[INS] : 0.f;
        __syncthreads();
        const bs8 afx = *(const bs8*)&xh0[0][col][aoff];
        const bs8 af0 = *(const bs8*)&xh1[0][col][0 * 32 + aoff];
        const bs8 af1 = *(const bs8*)&xh1[0][col][1 * 32 + aoff];
        const bs8 af2 = *(const bs8*)&xh1[0][col][2 * 32 + aoff];
        const bs8 af3 = *(const bs8*)&xh1[0][col][3 * 32 + aoff];
        f4 acc0_0 = {0.f,0.f,0.f,0.f}, acc0_1 = {0.f,0.f,0.f,0.f};
        f4 acc0_2 = {0.f,0.f,0.f,0.f}, acc0_3 = {0.f,0.f,0.f,0.f};
        L0K(0, afx) L0K(1, af0) L0K(2, af1) L0K(3, af2) L0K(4, af3)
        CELL4_0(1)
        xv = xnext;
    }

    // ---- steady state: t=1 single, then 255 literal-parity pairs ----
    STEP(1, 0, 1)
    for (int t = 2; t < SEQ; t += 2) {
        STEP(0, 1, t)
        STEP(1, 0, t + 1)
    }

    // ---- epilogue: L1/CELL1 for t = SEQ-1 (reads parity 0, writes q=1) ----
    {
        __syncthreads();
        const bs8 af0 = *(const bs8*)&xh1[0][col][0 * 32 + aoff];
        const bs8 af1 = *(const bs8*)&xh1[0][col][1 * 32 + aoff];
        const bs8 af2 = *(const bs8*)&xh1[0][col][2 * 32 + aoff];
        const bs8 af3 = *(const bs8*)&xh1[0][col][3 * 32 + aoff];
        const bs8 af4 = *(const bs8*)&xh1[0][col][4 * 32 + aoff];
        const bs8 af5 = *(const bs8*)&xh1[0][col][5 * 32 + aoff];
        const bs8 af6 = *(const bs8*)&xh1[0][col][6 * 32 + aoff];
        const bs8 af7 = *(const bs8*)&xh1[0][col][7 * 32 + aoff];
        f4 acc1_0 = {b1_0, b1_0, b1_0, b1_0};
        f4 acc1_1 = {b1_1, b1_1, b1_1, b1_1};
        f4 acc1_2 = {b1_2, b1_2, b1_2, b1_2};
        f4 acc1_3 = {b1_3, b1_3, b1_3, b1_3};
        L1KR(0, af0) L1KR(1, af1) L1KR(2, af2) L1KR(3, af3)
        L1KL(4, af4) L1KL(5, af5) L1KL(6, af6) L1KL(7, af7)
        float g0_, g1_, g2_, g3_;
        CELL1H(0, g0_) CELL1H(1, g1_) CELL1H(2, g2_) CELL1H(3, g3_)
        STOREPAIR(g0_, g1_, 0, 1, HID) STOREPAIR(g2_, g3_, 1, 1, HID)
    }
    __syncthreads();

    // ---- final FC (128 -> 1) + sigmoid; h1(SEQ-1) lives in xh1[1][.][HID+..] ----
    if (tid < BC) {
        float s = bfc[0];
#pragma unroll 8
        for (int k2 = 0; k2 < HID; ++k2)
            s += bf2f(xh1[1][tid][HID + k2]) * Wfc[k2];
        out[b0 + tid] = sigm(s);
    }
}

extern "C" void kernel_launch(void* const* d_in, const int* in_sizes, int n_in,
                              void* d_out, int out_size, void* d_ws, size_t ws_size,
                              hipStream_t stream) {
    const float* x    = (const float*)d_in[0];
    const float* Wih0 = (const float*)d_in[1];
    const float* Whh0 = (const float*)d_in[2];
    const float* bih0 = (const float*)d_in[3];
    const float* bhh0 = (const float*)d_in[4];
    const float* Wih1 = (const float*)d_in[5];
    const float* Whh1 = (const float*)d_in[6];
    const float* bih1 = (const float*)d_in[7];
    const float* bhh1 = (const float*)d_in[8];
    const float* Wfc  = (const float*)d_in[9];
    const float* bfc  = (const float*)d_in[10];
    float* out = (float*)d_out;
    short* wsw = (short*)d_ws;   // 426 KB of bf16 fragment-ordered weights

    int nfrag = NFRAG0 + NFRAG1;
    lstm_prep<<<(nfrag + 255) / 256, 256, 0, stream>>>(Wih0, Whh0, bih0, bhh0,
                                                       Wih1, Whh1, wsw);
    dim3 grid(2048 / BC);   // 128 blocks, 1 per CU
    dim3 block(512);        // 8 waves; each wave owns 16 hidden units
    lstm_fused<<<grid, block, 0, stream>>>(x, Wfc, bfc, bih1, bhh1, wsw, out);
}